// Round 9
// baseline (471.293 us; speedup 1.0000x reference)
//
#include <hip/hip_runtime.h>
#include <math.h>

// SQVAE forward on MI355X. N=16384 rows, D=512, K=1024 codes, B=8.
// R14: dist_fused re-tiled 256x256 -> 128x128 (4 waves, dbuf 2x32KB = 64KB
// LDS) so 2 blocks co-reside per CU (grid 1024). R13's lesson: the per-step
// cost is an exposed convoy (all waves at vmcnt+barrier, 1 block/CU = no one
// computing); occupancy interleaves it. Depth-1 prefetch + counted vmcnt(8)
// retained (R12-proven). gemm_bt BK=64 + zq-on-gemm_bt kept from R13
// (neutral-to-positive). softmax __expf/__logf kept (R12-proven).
#define NROWS 16384
#define DIM   512
#define KCODE 1024

typedef __attribute__((ext_vector_type(8))) __bf16 bf16x8;
typedef __attribute__((ext_vector_type(4))) float f32x4;

__device__ __forceinline__ float wave_reduce_sum(float v) {
  #pragma unroll
  for (int m = 1; m < 64; m <<= 1) v += __shfl_xor(v, m, 64);
  return v;
}
__device__ __forceinline__ float wave_reduce_max(float v) {
  #pragma unroll
  for (int m = 1; m < 64; m <<= 1) v = fmaxf(v, __shfl_xor(v, m, 64));
  return v;
}
__device__ __forceinline__ unsigned short f2bf(float f) {
  union { float f; unsigned u; } v; v.f = f;
  unsigned r = v.u + 0x7FFFu + ((v.u >> 16) & 1u);  // RNE
  return (unsigned short)(r >> 16);
}
__device__ __forceinline__ float bf2f(unsigned short h) {
  union { unsigned u; float f; } v; v.u = ((unsigned)h) << 16;
  return v.f;
}
__device__ __forceinline__ uint4 pack8(const float* x) {
  uint4 r;
  r.x = (unsigned)f2bf(x[0]) | ((unsigned)f2bf(x[1]) << 16);
  r.y = (unsigned)f2bf(x[2]) | ((unsigned)f2bf(x[3]) << 16);
  r.z = (unsigned)f2bf(x[4]) | ((unsigned)f2bf(x[5]) << 16);
  r.w = (unsigned)f2bf(x[6]) | ((unsigned)f2bf(x[7]) << 16);
  return r;
}

// async global->LDS, 16B per lane. LDS dst must be wave-uniform base;
// HW writes base + lane*16.
__device__ __forceinline__ void glds16(const void* g, void* lds) {
  __builtin_amdgcn_global_load_lds(
      (const __attribute__((address_space(1))) unsigned int*)g,
      (__attribute__((address_space(3))) unsigned int*)lds, 16, 0, 0);
}

// ---------------------------------------------------------------------------
// dist_fused: logits = -wq*(znorm + cnorm - 2*(zh@cbh^T + zl@cbh^T + zh@cbl^T))
// 128x128 tile, 256 thr (4 waves 2x2, per-wave 64x64), grid 1024, 16 K-steps
// BK=32. Per step: stage zh/zl/cbh/cbl panels (32KB) via glds16 in fragment-
// linear chunks (16r x 32k = 1KB), fire 48 MFMA/wave. Dbuf 2x32KB = 64KB
// LDS -> 2 blocks/CU; one block computes while the other drains vmcnt.
// Depth-1 prefetch: 8 own loads/wave/step, vmcnt(8) retires cur.
// ---------------------------------------------------------------------------
__global__ __launch_bounds__(256) void dist_fused(
    const unsigned short* __restrict__ zhp, const unsigned short* __restrict__ zlp,
    const unsigned short* __restrict__ cbh, const unsigned short* __restrict__ cbl,
    const float* __restrict__ znorm, const float* __restrict__ cnorm,
    const float* __restrict__ lpq, float* __restrict__ outf) {
  __shared__ char smem[65536];  // 2 halves x (zh 8K | zl 8K | cbh 8K | cbl 8K)
  const int t = threadIdx.x;
  const int l = t & 63, w = t >> 6;   // 4 waves
  const int wm = w >> 1, wn = w & 1;  // 2 x 2 wave grid
  const int b = blockIdx.x;
  const int xcd = b & 7, j = b >> 3;  // 128 m-tiles x 8 n-tiles
  const int m0 = (xcd * 16 + j / 8) * 128;
  const int n0 = (j % 8) * 128;

  f32x4 acc[4][4];
  #pragma unroll
  for (int i = 0; i < 4; ++i)
    #pragma unroll
    for (int jj = 0; jj < 4; ++jj) acc[i][jj] = (f32x4){0.f, 0.f, 0.f, 0.f};

  // staging: wave w stages chunks {w, w+4} of each operand (chunk = 16rx32k)
  const int row = l & 15;
  const int kcol = (l >> 4) * 8;
  const size_t aLo = (size_t)(m0 + w * 16 + row) * 512 + kcol;
  const size_t aHi = aLo + (size_t)64 * 512;
  const size_t bLo = (size_t)(n0 + w * 16 + row) * 512 + kcol;
  const size_t bHi = bLo + (size_t)64 * 512;
  const int dLo = w * 1024, dHi = (w + 4) * 1024;

  auto issue = [&](int s) {
    char* hb = smem + (s & 1) * 32768;
    const int kt = s * 32;
    glds16(zhp + aLo + kt, hb + dLo);
    glds16(zhp + aHi + kt, hb + dHi);
    glds16(zlp + aLo + kt, hb + 8192 + dLo);
    glds16(zlp + aHi + kt, hb + 8192 + dHi);
    glds16(cbh + bLo + kt, hb + 16384 + dLo);
    glds16(cbh + bHi + kt, hb + 16384 + dHi);
    glds16(cbl + bLo + kt, hb + 24576 + dLo);
    glds16(cbl + bHi + kt, hb + 24576 + dHi);
  };

  issue(0);  // 8 loads outstanding
  #pragma unroll 1
  for (int s = 0; s < 16; ++s) {
    if (s + 1 < 16) {
      issue(s + 1);  // 16 outstanding; oldest 8 are this step's
      asm volatile("s_waitcnt vmcnt(8)" ::: "memory");
    } else {
      asm volatile("s_waitcnt vmcnt(0)" ::: "memory");
    }
    __builtin_amdgcn_s_barrier();
    const char* hb = smem + (s & 1) * 32768;
    bf16x8 af[4], bh_[4], bl_[4];
    #pragma unroll
    for (int i = 0; i < 4; ++i) {
      bh_[i] = *(const bf16x8*)(hb + 16384 + (wn * 4 + i) * 1024 + l * 16);
      bl_[i] = *(const bf16x8*)(hb + 24576 + (wn * 4 + i) * 1024 + l * 16);
    }
    #pragma unroll
    for (int i = 0; i < 4; ++i)
      af[i] = *(const bf16x8*)(hb + (wm * 4 + i) * 1024 + l * 16);  // zh
    #pragma unroll
    for (int mi = 0; mi < 4; ++mi)
      #pragma unroll
      for (int ni = 0; ni < 4; ++ni) {
        acc[mi][ni] = __builtin_amdgcn_mfma_f32_16x16x32_bf16(af[mi], bh_[ni], acc[mi][ni], 0, 0, 0);
        acc[mi][ni] = __builtin_amdgcn_mfma_f32_16x16x32_bf16(af[mi], bl_[ni], acc[mi][ni], 0, 0, 0);
      }
    #pragma unroll
    for (int i = 0; i < 4; ++i)
      af[i] = *(const bf16x8*)(hb + 8192 + (wm * 4 + i) * 1024 + l * 16);  // zl
    #pragma unroll
    for (int mi = 0; mi < 4; ++mi)
      #pragma unroll
      for (int ni = 0; ni < 4; ++ni)
        acc[mi][ni] = __builtin_amdgcn_mfma_f32_16x16x32_bf16(af[mi], bh_[ni], acc[mi][ni], 0, 0, 0);
    __builtin_amdgcn_s_barrier();  // reads done before next overwrite
  }

  // ---- Epilogue via per-wave LDS slab (16 rows x 64 cols, stride 68) ----
  float* slab = (float*)(smem + w * 4352);
  const int q = l >> 4, c16 = l & 15;
  const int c4 = (l & 15) * 4;
  const float wq = 0.5f / fmaxf(expf(lpq[0]), 1e-10f);

  #pragma unroll
  for (int mi = 0; mi < 4; ++mi) {
    __syncthreads();
    #pragma unroll
    for (int ni = 0; ni < 4; ++ni)
      #pragma unroll
      for (int r = 0; r < 4; ++r)
        slab[(q * 4 + r) * 68 + ni * 16 + c16] = acc[mi][ni][r];
    __syncthreads();
    #pragma unroll
    for (int pp = 0; pp < 4; ++pp) {
      const int rw = pp * 4 + q;  // 0..15
      const float4 v4 = *(const float4*)&slab[rw * 68 + c4];
      const int m = m0 + wm * 64 + mi * 16 + rw;
      const int nc = n0 + wn * 64 + c4;
      const float zn = znorm[m];
      const float4 cn = *(const float4*)&cnorm[nc];
      float4 o;
      o.x = -wq * (zn + cn.x - 2.f * v4.x);
      o.y = -wq * (zn + cn.y - 2.f * v4.y);
      o.z = -wq * (zn + cn.z - 2.f * v4.z);
      o.w = -wq * (zn + cn.w - 2.f * v4.w);
      *(float4*)&outf[(size_t)m * KCODE + nc] = o;
    }
  }
}

// ---------------------------------------------------------------------------
// gemm_bt: 128x128 tile, BK=64, dbuf 2x32KB, depth-1 prefetch vmcnt(8).
// Serves enc/dec GEMMs (EPI 0: bias+relu->bf16) AND the zq GEMM (EPI 2:
// zq->bf16 + kldc). Chunk = 16 rows x 64 k = 2KB as two 1KB K=32 slices.
// ---------------------------------------------------------------------------
template <int EPI, int K, int N, int LDA>
__global__ __launch_bounds__(256) void gemm_bt(
    const unsigned short* A0, const unsigned short* B0,
    const float* __restrict__ bias, const float* __restrict__ lpq,
    const unsigned short* __restrict__ zh, const unsigned short* __restrict__ zl,
    float* __restrict__ kldc, unsigned short* __restrict__ outb) {
  __shared__ char smem[65536];  // 2 halves x (A 16K | B 16K); slab overlays
  const int t = threadIdx.x;
  const int l = t & 63, w = t >> 6;
  const int wm = w >> 1, wn = w & 1;
  const int NTN = N / 128;
  const int b = blockIdx.x;
  const int xcd = b & 7;
  const int j = b >> 3;
  const int m0 = (xcd * 16 + j / NTN) * 128;
  const int n0 = (j % NTN) * 128;

  f32x4 acc[4][4];
  #pragma unroll
  for (int i = 0; i < 4; ++i)
    #pragma unroll
    for (int jj = 0; jj < 4; ++jj) acc[i][jj] = (f32x4){0.f, 0.f, 0.f, 0.f};

  const int row = l & 15;
  const int kcol = (l >> 4) * 8;
  const size_t oA0 = (size_t)(m0 + w * 16 + row) * LDA + kcol;   // chunk w
  const size_t oA1 = oA0 + (size_t)64 * LDA;                     // chunk w+4
  const size_t oB0 = (size_t)(n0 + w * 16 + row) * K + kcol;
  const size_t oB1 = oB0 + (size_t)64 * K;
  const int dLo = w * 2048, dHi = (w + 4) * 2048;

  constexpr int NSTEP = K / 64;

  auto issue = [&](int ss) {
    char* hb = smem + (ss & 1) * 32768;
    const int kt = ss * 64;
    #pragma unroll
    for (int js = 0; js < 2; ++js) {
      const int ko = kt + js * 32;
      const int dj = js * 1024;
      glds16(A0 + oA0 + ko, hb + dLo + dj);
      glds16(A0 + oA1 + ko, hb + dHi + dj);
      glds16(B0 + oB0 + ko, hb + 16384 + dLo + dj);
      glds16(B0 + oB1 + ko, hb + 16384 + dHi + dj);
    }
  };

  issue(0);  // 8 loads outstanding
  #pragma unroll 1
  for (int s = 0; s < NSTEP; ++s) {
    if (s + 1 < NSTEP) {
      issue(s + 1);  // 16 outstanding; oldest 8 are this step's
      asm volatile("s_waitcnt vmcnt(8)" ::: "memory");
    } else {
      asm volatile("s_waitcnt vmcnt(0)" ::: "memory");
    }
    __builtin_amdgcn_s_barrier();
    const char* hb = smem + (s & 1) * 32768;
    #pragma unroll
    for (int js = 0; js < 2; ++js) {
      const int dj = js * 1024;
      bf16x8 af[4], bfr[4];
      #pragma unroll
      for (int i = 0; i < 4; ++i) {
        af[i]  = *(const bf16x8*)(hb + (wm * 4 + i) * 2048 + dj + l * 16);
        bfr[i] = *(const bf16x8*)(hb + 16384 + (wn * 4 + i) * 2048 + dj + l * 16);
      }
      #pragma unroll
      for (int mi = 0; mi < 4; ++mi)
        #pragma unroll
        for (int ni = 0; ni < 4; ++ni)
          acc[mi][ni] = __builtin_amdgcn_mfma_f32_16x16x32_bf16(af[mi], bfr[ni], acc[mi][ni], 0, 0, 0);
    }
    __builtin_amdgcn_s_barrier();
  }

  // ---- Epilogue via per-wave LDS slab ----
  float* slab = (float*)(smem + w * 4352);
  const int q = l >> 4, c16 = l & 15;
  const int c4 = (l & 15) * 4;
  const float wq = (EPI == 2) ? 0.5f / fmaxf(expf(lpq[0]), 1e-10f) : 0.f;
  float local = 0.f;

  #pragma unroll
  for (int mi = 0; mi < 4; ++mi) {
    __syncthreads();
    #pragma unroll
    for (int ni = 0; ni < 4; ++ni)
      #pragma unroll
      for (int r = 0; r < 4; ++r)
        slab[(q * 4 + r) * 68 + ni * 16 + c16] = acc[mi][ni][r];
    __syncthreads();
    #pragma unroll
    for (int pp = 0; pp < 4; ++pp) {
      const int rw = pp * 4 + q;
      const float4 v4 = *(const float4*)&slab[rw * 68 + c4];
      float v[4] = {v4.x, v4.y, v4.z, v4.w};
      const int m = m0 + wm * 64 + mi * 16 + rw;
      const int nc = n0 + wn * 64 + c4;
      if (EPI == 0) {
        const float4 b4 = *(const float4*)&bias[nc];
        v[0] = fmaxf(v[0] + b4.x, 0.f);
        v[1] = fmaxf(v[1] + b4.y, 0.f);
        v[2] = fmaxf(v[2] + b4.z, 0.f);
        v[3] = fmaxf(v[3] + b4.w, 0.f);
        uint2 st;
        st.x = (unsigned)f2bf(v[0]) | ((unsigned)f2bf(v[1]) << 16);
        st.y = (unsigned)f2bf(v[2]) | ((unsigned)f2bf(v[3]) << 16);
        *(uint2*)&outb[(size_t)m * N + nc] = st;
      } else {
        const uint2 h2 = *(const uint2*)&zh[(size_t)m * N + nc];
        const uint2 l2 = *(const uint2*)&zl[(size_t)m * N + nc];
        const float z0 = bf2f((unsigned short)(h2.x & 0xFFFF)) + bf2f((unsigned short)(l2.x & 0xFFFF));
        const float z1 = bf2f((unsigned short)(h2.x >> 16))    + bf2f((unsigned short)(l2.x >> 16));
        const float z2 = bf2f((unsigned short)(h2.y & 0xFFFF)) + bf2f((unsigned short)(l2.y & 0xFFFF));
        const float z3 = bf2f((unsigned short)(h2.y >> 16))    + bf2f((unsigned short)(l2.y >> 16));
        const float d0 = z0 - v[0], d1 = z1 - v[1], d2 = z2 - v[2], d3 = z3 - v[3];
        local += d0 * d0 + d1 * d1 + d2 * d2 + d3 * d3;
        uint2 st;
        st.x = (unsigned)f2bf(v[0]) | ((unsigned)f2bf(v[1]) << 16);
        st.y = (unsigned)f2bf(v[2]) | ((unsigned)f2bf(v[3]) << 16);
        *(uint2*)&outb[(size_t)m * N + nc] = st;
      }
    }
  }
  if (EPI == 2) {
    local = wave_reduce_sum(local) * wq;
    if (l == 0) atomicAdd(kldc, local);
  }
}

// ---------------------------------------------------------------------------
// Row LayerNorm over bf16 input [M][512]. MODE 0: bf16 out. MODE 1: hi/lo
// split out + row norm^2. MODE 2: fp32 out (final x_rec).
// ---------------------------------------------------------------------------
template <int MODE>
__global__ __launch_bounds__(256) void ln_rows(
    const unsigned short* __restrict__ X, const float* __restrict__ g,
    const float* __restrict__ be, unsigned short* __restrict__ Y,
    unsigned short* __restrict__ Yl, float* __restrict__ znorm,
    float* __restrict__ Yf) {
  const int l = threadIdx.x & 63, wv = threadIdx.x >> 6;
  float gv[8], bv[8];
  {
    const float4 a = *(const float4*)&g[l * 8];
    const float4 b = *(const float4*)&g[l * 8 + 4];
    gv[0] = a.x; gv[1] = a.y; gv[2] = a.z; gv[3] = a.w;
    gv[4] = b.x; gv[5] = b.y; gv[6] = b.z; gv[7] = b.w;
    const float4 c = *(const float4*)&be[l * 8];
    const float4 d = *(const float4*)&be[l * 8 + 4];
    bv[0] = c.x; bv[1] = c.y; bv[2] = c.z; bv[3] = c.w;
    bv[4] = d.x; bv[5] = d.y; bv[6] = d.z; bv[7] = d.w;
  }
  const int row0 = blockIdx.x * 32 + wv * 8;
  for (int rr = 0; rr < 8; ++rr) {
    const int row = row0 + rr;
    const uint4 raw = *(const uint4*)&X[(size_t)row * 512 + l * 8];
    float v[8];
    const unsigned rw[4] = {raw.x, raw.y, raw.z, raw.w};
    #pragma unroll
    for (int i = 0; i < 4; ++i) {
      v[2 * i]     = bf2f((unsigned short)(rw[i] & 0xFFFF));
      v[2 * i + 1] = bf2f((unsigned short)(rw[i] >> 16));
    }
    float s = 0.f, ss = 0.f;
    #pragma unroll
    for (int i = 0; i < 8; ++i) { s += v[i]; ss += v[i] * v[i]; }
    #pragma unroll
    for (int m = 1; m < 64; m <<= 1) {
      s += __shfl_xor(s, m, 64);
      ss += __shfl_xor(ss, m, 64);
    }
    const float mean = s * (1.f / 512.f);
    const float var = ss * (1.f / 512.f) - mean * mean;
    const float rstd = rsqrtf(var + 1e-5f);
    float y[8];
    #pragma unroll
    for (int i = 0; i < 8; ++i) y[i] = (v[i] - mean) * rstd * gv[i] + bv[i];
    if (MODE == 0) {
      *(uint4*)&Y[(size_t)row * 512 + l * 8] = pack8(y);
    } else if (MODE == 1) {
      float lo[8], ns = 0.f;
      unsigned short hx[8];
      #pragma unroll
      for (int i = 0; i < 8; ++i) {
        hx[i] = f2bf(y[i]);
        lo[i] = y[i] - bf2f(hx[i]);
        ns += y[i] * y[i];
      }
      uint4 hv;
      hv.x = (unsigned)hx[0] | ((unsigned)hx[1] << 16);
      hv.y = (unsigned)hx[2] | ((unsigned)hx[3] << 16);
      hv.z = (unsigned)hx[4] | ((unsigned)hx[5] << 16);
      hv.w = (unsigned)hx[6] | ((unsigned)hx[7] << 16);
      *(uint4*)&Y[(size_t)row * 512 + l * 8] = hv;
      *(uint4*)&Yl[(size_t)row * 512 + l * 8] = pack8(lo);
      ns = wave_reduce_sum(ns);
      if (l == 0) znorm[row] = ns;
    } else {
      float4 o0, o1;
      o0.x = y[0]; o0.y = y[1]; o0.z = y[2]; o0.w = y[3];
      o1.x = y[4]; o1.y = y[5]; o1.z = y[6]; o1.w = y[7];
      *(float4*)&Yf[(size_t)row * 512 + l * 8] = o0;
      *(float4*)&Yf[(size_t)row * 512 + l * 8 + 4] = o1;
    }
  }
}

// ---------------------------------------------------------------------------
// Prep kernels.
// ---------------------------------------------------------------------------
__global__ __launch_bounds__(256) void convert_f32_bf16(
    const float* __restrict__ X, unsigned short* __restrict__ Y) {
  const size_t i = ((size_t)blockIdx.x * 256 + threadIdx.x) * 8;
  const float4 a = *(const float4*)&X[i];
  const float4 b = *(const float4*)&X[i + 4];
  float v[8] = {a.x, a.y, a.z, a.w, b.x, b.y, b.z, b.w};
  *(uint4*)&Y[i] = pack8(v);
}

// codebook -> hi/lo bf16 + ||c||^2
__global__ __launch_bounds__(256) void prep_cb(
    const float* __restrict__ CB, unsigned short* __restrict__ H,
    unsigned short* __restrict__ L, float* __restrict__ cnorm) {
  const int wv = threadIdx.x >> 6, l = threadIdx.x & 63;
  const int r = blockIdx.x * 4 + wv;
  const float* row = &CB[(size_t)r * 512 + l * 8];
  const float4 a = *(const float4*)row;
  const float4 b = *(const float4*)(row + 4);
  float x[8] = {a.x, a.y, a.z, a.w, b.x, b.y, b.z, b.w};
  float s = 0.f, lo[8];
  unsigned short hi[8];
  #pragma unroll
  for (int i = 0; i < 8; ++i) {
    s += x[i] * x[i];
    hi[i] = f2bf(x[i]);
    lo[i] = x[i] - bf2f(hi[i]);
  }
  uint4 hv;
  hv.x = (unsigned)hi[0] | ((unsigned)hi[1] << 16);
  hv.y = (unsigned)hi[2] | ((unsigned)hi[3] << 16);
  hv.z = (unsigned)hi[4] | ((unsigned)hi[5] << 16);
  hv.w = (unsigned)hi[6] | ((unsigned)hi[7] << 16);
  *(uint4*)&H[(size_t)r * 512 + l * 8] = hv;
  *(uint4*)&L[(size_t)r * 512 + l * 8] = pack8(lo);
  s = wave_reduce_sum(s);
  if (l == 0) cnorm[r] = s;
}

// in [R][C] fp32 -> out [C][R] bf16, LDS-tiled 32x32, coalesced both sides.
__global__ __launch_bounds__(256) void transpose_f32_bf16(
    const float* __restrict__ in, unsigned short* __restrict__ out, int R, int C) {
  __shared__ float tile[32][33];
  const int ntc = C >> 5;
  const int c0 = (blockIdx.x % ntc) * 32, r0 = (blockIdx.x / ntc) * 32;
  const int tx = threadIdx.x & 31, ty = threadIdx.x >> 5;
  #pragma unroll
  for (int i = 0; i < 4; ++i)
    tile[ty + 8 * i][tx] = in[(size_t)(r0 + ty + 8 * i) * C + c0 + tx];
  __syncthreads();
  #pragma unroll
  for (int i = 0; i < 4; ++i)
    out[(size_t)(c0 + ty + 8 * i) * R + r0 + tx] = f2bf(tile[tx][ty + 8 * i]);
}

// ---------------------------------------------------------------------------
// Softmax stats + gumbel-softmax. __expf/__logf fast intrinsics; exp values
// cached in registers. Encodings bf16 into first half of logits rows.
// ---------------------------------------------------------------------------
__global__ __launch_bounds__(256) void softmax_gumbel(
    const float* logits, const float* __restrict__ U, unsigned short* E,
    float* __restrict__ colsum, float* __restrict__ kldd_acc) {
  __shared__ float cs[1024];
  __shared__ float kd[4];
  const int t = threadIdx.x;
  const int wv = t >> 6, l = t & 63;
  #pragma unroll
  for (int i = 0; i < 4; ++i) cs[t + 256 * i] = 0.f;
  __syncthreads();
  float psum[16];
  #pragma unroll
  for (int i = 0; i < 16; ++i) psum[i] = 0.f;
  float kldd = 0.f;
  const int nbase = blockIdx.x * 16 + wv * 4;

  for (int it = 0; it < 4; ++it) {
    const int row = nbase + it;
    const size_t off = (size_t)row * KCODE + 4 * l;
    float v[16];
    #pragma unroll
    for (int jj = 0; jj < 4; ++jj) {
      const float4 t4 = *(const float4*)&logits[off + 256 * jj];
      v[4 * jj + 0] = t4.x; v[4 * jj + 1] = t4.y; v[4 * jj + 2] = t4.z; v[4 * jj + 3] = t4.w;
    }
    float m = v[0];
    #pragma unroll
    for (int i = 1; i < 16; ++i) m = fmaxf(m, v[i]);
    m = wave_reduce_max(m);
    float e[16], se = 0.f;
    #pragma unroll
    for (int i = 0; i < 16; ++i) { e[i] = __expf(v[i] - m); se += e[i]; }
    se = wave_reduce_sum(se);
    const float lz = __logf(se);
    const float inv_se = 1.f / se;
    float pl = 0.f;
    #pragma unroll
    for (int i = 0; i < 16; ++i) {
      const float p = e[i] * inv_se;
      psum[i] += p;
      pl += p * (v[i] - m - lz);
    }
    kldd += pl;
    float y[16];
    #pragma unroll
    for (int jj = 0; jj < 4; ++jj) {
      const float4 t4 = *(const float4*)&U[off + 256 * jj];
      y[4 * jj + 0] = v[4 * jj + 0] - __logf(-__logf(t4.x + 1e-10f) + 1e-10f);
      y[4 * jj + 1] = v[4 * jj + 1] - __logf(-__logf(t4.y + 1e-10f) + 1e-10f);
      y[4 * jj + 2] = v[4 * jj + 2] - __logf(-__logf(t4.z + 1e-10f) + 1e-10f);
      y[4 * jj + 3] = v[4 * jj + 3] - __logf(-__logf(t4.w + 1e-10f) + 1e-10f);
    }
    float m2 = y[0];
    #pragma unroll
    for (int i = 1; i < 16; ++i) m2 = fmaxf(m2, y[i]);
    m2 = wave_reduce_max(m2);
    float ey[16], s2 = 0.f;
    #pragma unroll
    for (int i = 0; i < 16; ++i) { ey[i] = __expf(y[i] - m2); s2 += ey[i]; }
    s2 = wave_reduce_sum(s2);
    const float inv = 1.f / s2;
    #pragma unroll
    for (int jj = 0; jj < 4; ++jj) {
      ushort4 e4;
      e4.x = f2bf(ey[4 * jj + 0] * inv);
      e4.y = f2bf(ey[4 * jj + 1] * inv);
      e4.z = f2bf(ey[4 * jj + 2] * inv);
      e4.w = f2bf(ey[4 * jj + 3] * inv);
      *(ushort4*)&E[(size_t)row * 2048 + 4 * l + 256 * jj] = e4;
    }
  }
  #pragma unroll
  for (int jj = 0; jj < 4; ++jj)
    #pragma unroll
    for (int c = 0; c < 4; ++c)
      atomicAdd(&cs[256 * jj + 4 * l + c], psum[4 * jj + c]);
  kldd = wave_reduce_sum(kldd);
  if (l == 0) kd[wv] = kldd;
  __syncthreads();
  #pragma unroll
  for (int i = 0; i < 4; ++i) {
    const float vv = cs[t + 256 * i];
    if (vv != 0.f) atomicAdd(&colsum[t + 256 * i], vv);
  }
  if (t == 0) atomicAdd(kldd_acc, kd[0] + kd[1] + kd[2] + kd[3]);
}

__global__ __launch_bounds__(256) void finalize(
    const float* __restrict__ colsum, const float* __restrict__ scal,
    float* __restrict__ out) {
  const int t = threadIdx.x;
  float ent = 0.f;
  #pragma unroll
  for (int jj = 0; jj < 4; ++jj) {
    const float a = colsum[t + 256 * jj] * (1.f / 16384.f);
    ent += a * logf(a + 1e-7f);
  }
  ent = wave_reduce_sum(ent);
  __shared__ float red[4];
  if ((t & 63) == 0) red[t >> 6] = ent;
  __syncthreads();
  if (t == 0) {
    const float tot = red[0] + red[1] + red[2] + red[3];
    out[0] = (scal[0] + scal[1]) * (1.f / 8.f);
    out[1] = expf(-tot);
  }
}

extern "C" void kernel_launch(void* const* d_in, const int* in_sizes, int n_in,
                              void* d_out, int out_size, void* d_ws, size_t ws_size,
                              hipStream_t stream) {
  const float* x      = (const float*)d_in[0];
  const float* gu     = (const float*)d_in[1];
  const float* enc_w1 = (const float*)d_in[2];
  const float* enc_b1 = (const float*)d_in[3];
  const float* enc_g1 = (const float*)d_in[4];
  const float* enc_e1 = (const float*)d_in[5];
  const float* enc_w2 = (const float*)d_in[6];
  const float* enc_b2 = (const float*)d_in[7];
  const float* enc_g2 = (const float*)d_in[8];
  const float* enc_e2 = (const float*)d_in[9];
  const float* dec_w1 = (const float*)d_in[10];
  const float* dec_b1 = (const float*)d_in[11];
  const float* dec_g1 = (const float*)d_in[12];
  const float* dec_e1 = (const float*)d_in[13];
  const float* dec_w2 = (const float*)d_in[14];
  const float* dec_b2 = (const float*)d_in[15];
  const float* dec_g2 = (const float*)d_in[16];
  const float* dec_e2 = (const float*)d_in[17];
  const float* cb     = (const float*)d_in[18];
  const float* lpq    = (const float*)d_in[19];
  float* out = (float*)d_out;
  char* wsb = (char*)d_ws;

  float*          logits = (float*)(wsb + 0);                  // 64 MB
  unsigned short* Eb     = (unsigned short*)(wsb + 0);         // overlay, pitch 2048
  unsigned short* t1     = (unsigned short*)(wsb + 67108864);  // 16 MB
  unsigned short* xb     = (unsigned short*)(wsb + 83886080);  // 16 MB (xb then zh)
  unsigned short* zh     = xb;
  unsigned short* hq     = (unsigned short*)(wsb + 100663296); // 16 MB
  unsigned short* zl     = (unsigned short*)(wsb + 117440512); // 16 MB
  unsigned short* wt0    = (unsigned short*)(wsb + 134217728);
  unsigned short* wt1    = wt0 + 262144;
  unsigned short* wt2    = wt1 + 262144;
  unsigned short* wt3    = wt2 + 262144;
  unsigned short* cbh    = (unsigned short*)(wsb + 136314880);
  unsigned short* cbl    = (unsigned short*)(wsb + 137363456);
  unsigned short* cbT    = (unsigned short*)(wsb + 138412032);
  float*          znorm  = (float*)(wsb + 139460608);
  float*          cnorm  = (float*)(wsb + 139526144);
  float*          colsum = (float*)(wsb + 139530240);
  float*          scal   = (float*)(wsb + 139534336);

  hipMemsetAsync(colsum, 0, 4096 + 16, stream);

  convert_f32_bf16<<<4096, 256, 0, stream>>>(x, xb);
  prep_cb<<<256, 256, 0, stream>>>(cb, cbh, cbl, cnorm);
  transpose_f32_bf16<<<256, 256, 0, stream>>>(enc_w1, wt0, 512, 512);
  transpose_f32_bf16<<<256, 256, 0, stream>>>(enc_w2, wt1, 512, 512);
  transpose_f32_bf16<<<256, 256, 0, stream>>>(dec_w1, wt2, 512, 512);
  transpose_f32_bf16<<<256, 256, 0, stream>>>(dec_w2, wt3, 512, 512);
  transpose_f32_bf16<<<512, 256, 0, stream>>>(cb, cbT, 1024, 512);

  gemm_bt<0, 512, 512, 512><<<512, 256, 0, stream>>>(
      xb, wt0, enc_b1, nullptr, nullptr, nullptr, nullptr, t1);
  ln_rows<0><<<512, 256, 0, stream>>>(t1, enc_g1, enc_e1, hq, nullptr, nullptr, nullptr);
  gemm_bt<0, 512, 512, 512><<<512, 256, 0, stream>>>(
      hq, wt1, enc_b2, nullptr, nullptr, nullptr, nullptr, t1);
  ln_rows<1><<<512, 256, 0, stream>>>(t1, enc_g2, enc_e2, zh, zl, znorm, nullptr);
  dist_fused<<<1024, 256, 0, stream>>>(
      zh, zl, cbh, cbl, znorm, cnorm, lpq, logits);
  softmax_gumbel<<<1024, 256, 0, stream>>>(logits, gu, Eb, colsum, &scal[0]);
  gemm_bt<2, 1024, 512, 2048><<<512, 256, 0, stream>>>(
      Eb, cbT, nullptr, lpq, zh, zl, &scal[1], hq);
  gemm_bt<0, 512, 512, 512><<<512, 256, 0, stream>>>(
      hq, wt2, dec_b1, nullptr, nullptr, nullptr, nullptr, t1);
  ln_rows<0><<<512, 256, 0, stream>>>(t1, dec_g1, dec_e1, zl, nullptr, nullptr, nullptr);
  gemm_bt<0, 512, 512, 512><<<512, 256, 0, stream>>>(
      zl, wt3, dec_b2, nullptr, nullptr, nullptr, nullptr, t1);
  ln_rows<2><<<512, 256, 0, stream>>>(t1, dec_g2, dec_e2, nullptr, nullptr, nullptr, out);
  finalize<<<1, 256, 0, stream>>>(colsum, scal, out + 8388608);
}

// Round 10
// 462.310 us; speedup vs baseline: 1.0194x; 1.0194x over previous
//
#include <hip/hip_runtime.h>
#include <math.h>

// SQVAE forward on MI355X. N=16384 rows, D=512, K=1024 codes, B=8.
// R15: dist_fused = R12's proven 256^2/depth-1/vmcnt(8) skeleton + 3-phase
// K-step split (T3/T5 mechanism, m196/m201): each step's 96 MFMA/wave split
// into 3 {ds_read cluster -> lgkmcnt(0) -> setprio(1) MFMA setprio(0) ->
// s_barrier} phases so the SIMD always has MFMA-ready waves while others
// issue reads. Buffer/sync discipline identical to R12. R13 (fat steps) and
// R14 (2 blocks/CU) both regressed to 77us; R12=63.5 is the 1-phase optimum.
#define NROWS 16384
#define DIM   512
#define KCODE 1024

typedef __attribute__((ext_vector_type(8))) __bf16 bf16x8;
typedef __attribute__((ext_vector_type(4))) float f32x4;

__device__ __forceinline__ float wave_reduce_sum(float v) {
  #pragma unroll
  for (int m = 1; m < 64; m <<= 1) v += __shfl_xor(v, m, 64);
  return v;
}
__device__ __forceinline__ float wave_reduce_max(float v) {
  #pragma unroll
  for (int m = 1; m < 64; m <<= 1) v = fmaxf(v, __shfl_xor(v, m, 64));
  return v;
}
__device__ __forceinline__ unsigned short f2bf(float f) {
  union { float f; unsigned u; } v; v.f = f;
  unsigned r = v.u + 0x7FFFu + ((v.u >> 16) & 1u);  // RNE
  return (unsigned short)(r >> 16);
}
__device__ __forceinline__ float bf2f(unsigned short h) {
  union { unsigned u; float f; } v; v.u = ((unsigned)h) << 16;
  return v.f;
}
__device__ __forceinline__ uint4 pack8(const float* x) {
  uint4 r;
  r.x = (unsigned)f2bf(x[0]) | ((unsigned)f2bf(x[1]) << 16);
  r.y = (unsigned)f2bf(x[2]) | ((unsigned)f2bf(x[3]) << 16);
  r.z = (unsigned)f2bf(x[4]) | ((unsigned)f2bf(x[5]) << 16);
  r.w = (unsigned)f2bf(x[6]) | ((unsigned)f2bf(x[7]) << 16);
  return r;
}

// async global->LDS, 16B per lane. LDS dst must be wave-uniform base;
// HW writes base + lane*16.
__device__ __forceinline__ void glds16(const void* g, void* lds) {
  __builtin_amdgcn_global_load_lds(
      (const __attribute__((address_space(1))) unsigned int*)g,
      (__attribute__((address_space(3))) unsigned int*)lds, 16, 0, 0);
}

// ---------------------------------------------------------------------------
// dist_fused: logits = -wq*(znorm + cnorm - 2*(zh@cbh^T + zl@cbh^T + zh@cbl^T))
// 256x256 tile, 512 thr (8 waves, 2x4), per-wave 128x64 out, 16 K-steps
// BK=32. Staging: zh/zl/cbh/cbl fragment-linear chunks, dbuf 2x64KB, depth-1
// prefetch + counted vmcnt(8) (R12-proven). NEW: 3 phases per step, each
// {reads -> lgkmcnt(0) -> setprio MFMA -> barrier} for read/MFMA role
// diversity across the 8 waves.
// ---------------------------------------------------------------------------
__global__ __launch_bounds__(512, 2) void dist_fused(
    const unsigned short* __restrict__ zhp, const unsigned short* __restrict__ zlp,
    const unsigned short* __restrict__ cbh, const unsigned short* __restrict__ cbl,
    const float* __restrict__ znorm, const float* __restrict__ cnorm,
    const float* __restrict__ lpq, float* __restrict__ outf) {
  __shared__ char smem[131072];  // 2 x (zh 16K | zl 16K | cbh 16K | cbl 16K)
  const int t = threadIdx.x;
  const int l = t & 63, w = t >> 6;   // 8 waves
  const int wm = w >> 2, wn = w & 3;  // 2 x 4 wave grid
  const int b = blockIdx.x;
  const int xcd = b & 7, j = b >> 3;
  const int m0 = (xcd * 8 + j / 4) * 256;  // 64 m-tiles, 8 per XCD
  const int n0 = (j % 4) * 256;

  f32x4 acc[8][4];
  #pragma unroll
  for (int i = 0; i < 8; ++i)
    #pragma unroll
    for (int jj = 0; jj < 4; ++jj) acc[i][jj] = (f32x4){0.f, 0.f, 0.f, 0.f};

  // staging: wave w stages chunks {w, w+8} of each operand (chunk = 16rx32k)
  const int row = l & 15;
  const int kcol = (l >> 4) * 8;
  const size_t aLo = (size_t)(m0 + w * 16 + row) * 512 + kcol;
  const size_t aHi = aLo + (size_t)128 * 512;
  const size_t bLo = (size_t)(n0 + w * 16 + row) * 512 + kcol;
  const size_t bHi = bLo + (size_t)128 * 512;

  auto issue = [&](int s) {
    char* hb = smem + (s & 1) * 65536;
    const int kt = s * 32;
    glds16(zhp + aLo + kt, hb + w * 1024);
    glds16(zhp + aHi + kt, hb + (w + 8) * 1024);
    glds16(zlp + aLo + kt, hb + 16384 + w * 1024);
    glds16(zlp + aHi + kt, hb + 16384 + (w + 8) * 1024);
    glds16(cbh + bLo + kt, hb + 32768 + w * 1024);
    glds16(cbh + bHi + kt, hb + 32768 + (w + 8) * 1024);
    glds16(cbl + bLo + kt, hb + 49152 + w * 1024);
    glds16(cbl + bHi + kt, hb + 49152 + (w + 8) * 1024);
  };

  issue(0);  // 8 loads outstanding
  #pragma unroll 1
  for (int s = 0; s < 16; ++s) {
    if (s + 1 < 16) {
      issue(s + 1);  // 16 outstanding; oldest 8 are this step's
      asm volatile("s_waitcnt vmcnt(8)" ::: "memory");
    } else {
      asm volatile("s_waitcnt vmcnt(0)" ::: "memory");
    }
    __builtin_amdgcn_s_barrier();  // all waves' half-s staging complete
    const char* hb = smem + (s & 1) * 65536;
    bf16x8 af[8], bh_[4], bl_[4];

    // ---- Phase A: read cbh frags + zh frags; MFMA zh x cbh ----
    #pragma unroll
    for (int i = 0; i < 4; ++i)
      bh_[i] = *(const bf16x8*)(hb + 32768 + (wn * 4 + i) * 1024 + l * 16);
    #pragma unroll
    for (int i = 0; i < 8; ++i)
      af[i] = *(const bf16x8*)(hb + (wm * 8 + i) * 1024 + l * 16);
    asm volatile("s_waitcnt lgkmcnt(0)" ::: "memory");
    __builtin_amdgcn_s_setprio(1);
    #pragma unroll
    for (int mi = 0; mi < 8; ++mi)
      #pragma unroll
      for (int ni = 0; ni < 4; ++ni)
        acc[mi][ni] = __builtin_amdgcn_mfma_f32_16x16x32_bf16(af[mi], bh_[ni], acc[mi][ni], 0, 0, 0);
    __builtin_amdgcn_s_setprio(0);
    __builtin_amdgcn_s_barrier();

    // ---- Phase B: read cbl frags; MFMA zh x cbl (af still live) ----
    #pragma unroll
    for (int i = 0; i < 4; ++i)
      bl_[i] = *(const bf16x8*)(hb + 49152 + (wn * 4 + i) * 1024 + l * 16);
    asm volatile("s_waitcnt lgkmcnt(0)" ::: "memory");
    __builtin_amdgcn_s_setprio(1);
    #pragma unroll
    for (int mi = 0; mi < 8; ++mi)
      #pragma unroll
      for (int ni = 0; ni < 4; ++ni)
        acc[mi][ni] = __builtin_amdgcn_mfma_f32_16x16x32_bf16(af[mi], bl_[ni], acc[mi][ni], 0, 0, 0);
    __builtin_amdgcn_s_setprio(0);
    __builtin_amdgcn_s_barrier();

    // ---- Phase C: read zl frags; MFMA zl x cbh (bh_ still live) ----
    #pragma unroll
    for (int i = 0; i < 8; ++i)
      af[i] = *(const bf16x8*)(hb + 16384 + (wm * 8 + i) * 1024 + l * 16);
    asm volatile("s_waitcnt lgkmcnt(0)" ::: "memory");
    __builtin_amdgcn_s_setprio(1);
    #pragma unroll
    for (int mi = 0; mi < 8; ++mi)
      #pragma unroll
      for (int ni = 0; ni < 4; ++ni)
        acc[mi][ni] = __builtin_amdgcn_mfma_f32_16x16x32_bf16(af[mi], bh_[ni], acc[mi][ni], 0, 0, 0);
    __builtin_amdgcn_s_setprio(0);
    __builtin_amdgcn_s_barrier();  // reads of half s done before overwrite
  }

  // ---- Epilogue via per-wave LDS slab (16 rows x 64 cols, stride 68) ----
  float* slab = (float*)(smem + w * 4352);
  const int q = l >> 4, c16 = l & 15;
  const int c4 = (l & 15) * 4;
  const float wq = 0.5f / fmaxf(expf(lpq[0]), 1e-10f);

  #pragma unroll
  for (int mi = 0; mi < 8; ++mi) {
    __syncthreads();
    #pragma unroll
    for (int ni = 0; ni < 4; ++ni)
      #pragma unroll
      for (int r = 0; r < 4; ++r)
        slab[(q * 4 + r) * 68 + ni * 16 + c16] = acc[mi][ni][r];
    __syncthreads();
    #pragma unroll
    for (int pp = 0; pp < 4; ++pp) {
      const int rw = pp * 4 + q;  // 0..15
      const float4 v4 = *(const float4*)&slab[rw * 68 + c4];
      const int m = m0 + wm * 128 + mi * 16 + rw;
      const int nc = n0 + wn * 64 + c4;
      const float zn = znorm[m];
      const float4 cn = *(const float4*)&cnorm[nc];
      float4 o;
      o.x = -wq * (zn + cn.x - 2.f * v4.x);
      o.y = -wq * (zn + cn.y - 2.f * v4.y);
      o.z = -wq * (zn + cn.z - 2.f * v4.z);
      o.w = -wq * (zn + cn.w - 2.f * v4.w);
      *(float4*)&outf[(size_t)m * KCODE + nc] = o;
    }
  }
}

// ---------------------------------------------------------------------------
// gemm_bt: 128x128 tile, BK=64, dbuf 2x32KB, depth-1 prefetch vmcnt(8).
// Serves enc/dec GEMMs (EPI 0: bias+relu->bf16) AND the zq GEMM (EPI 2:
// zq->bf16 + kldc). Chunk = 16 rows x 64 k = 2KB as two 1KB K=32 slices.
// ---------------------------------------------------------------------------
template <int EPI, int K, int N, int LDA>
__global__ __launch_bounds__(256) void gemm_bt(
    const unsigned short* A0, const unsigned short* B0,
    const float* __restrict__ bias, const float* __restrict__ lpq,
    const unsigned short* __restrict__ zh, const unsigned short* __restrict__ zl,
    float* __restrict__ kldc, unsigned short* __restrict__ outb) {
  __shared__ char smem[65536];  // 2 halves x (A 16K | B 16K); slab overlays
  const int t = threadIdx.x;
  const int l = t & 63, w = t >> 6;
  const int wm = w >> 1, wn = w & 1;
  const int NTN = N / 128;
  const int b = blockIdx.x;
  const int xcd = b & 7;
  const int j = b >> 3;
  const int m0 = (xcd * 16 + j / NTN) * 128;
  const int n0 = (j % NTN) * 128;

  f32x4 acc[4][4];
  #pragma unroll
  for (int i = 0; i < 4; ++i)
    #pragma unroll
    for (int jj = 0; jj < 4; ++jj) acc[i][jj] = (f32x4){0.f, 0.f, 0.f, 0.f};

  const int row = l & 15;
  const int kcol = (l >> 4) * 8;
  const size_t oA0 = (size_t)(m0 + w * 16 + row) * LDA + kcol;   // chunk w
  const size_t oA1 = oA0 + (size_t)64 * LDA;                     // chunk w+4
  const size_t oB0 = (size_t)(n0 + w * 16 + row) * K + kcol;
  const size_t oB1 = oB0 + (size_t)64 * K;
  const int dLo = w * 2048, dHi = (w + 4) * 2048;

  constexpr int NSTEP = K / 64;

  auto issue = [&](int ss) {
    char* hb = smem + (ss & 1) * 32768;
    const int kt = ss * 64;
    #pragma unroll
    for (int js = 0; js < 2; ++js) {
      const int ko = kt + js * 32;
      const int dj = js * 1024;
      glds16(A0 + oA0 + ko, hb + dLo + dj);
      glds16(A0 + oA1 + ko, hb + dHi + dj);
      glds16(B0 + oB0 + ko, hb + 16384 + dLo + dj);
      glds16(B0 + oB1 + ko, hb + 16384 + dHi + dj);
    }
  };

  issue(0);  // 8 loads outstanding
  #pragma unroll 1
  for (int s = 0; s < NSTEP; ++s) {
    if (s + 1 < NSTEP) {
      issue(s + 1);  // 16 outstanding; oldest 8 are this step's
      asm volatile("s_waitcnt vmcnt(8)" ::: "memory");
    } else {
      asm volatile("s_waitcnt vmcnt(0)" ::: "memory");
    }
    __builtin_amdgcn_s_barrier();
    const char* hb = smem + (s & 1) * 32768;
    #pragma unroll
    for (int js = 0; js < 2; ++js) {
      const int dj = js * 1024;
      bf16x8 af[4], bfr[4];
      #pragma unroll
      for (int i = 0; i < 4; ++i) {
        af[i]  = *(const bf16x8*)(hb + (wm * 4 + i) * 2048 + dj + l * 16);
        bfr[i] = *(const bf16x8*)(hb + 16384 + (wn * 4 + i) * 2048 + dj + l * 16);
      }
      #pragma unroll
      for (int mi = 0; mi < 4; ++mi)
        #pragma unroll
        for (int ni = 0; ni < 4; ++ni)
          acc[mi][ni] = __builtin_amdgcn_mfma_f32_16x16x32_bf16(af[mi], bfr[ni], acc[mi][ni], 0, 0, 0);
    }
    __builtin_amdgcn_s_barrier();
  }

  // ---- Epilogue via per-wave LDS slab ----
  float* slab = (float*)(smem + w * 4352);
  const int q = l >> 4, c16 = l & 15;
  const int c4 = (l & 15) * 4;
  const float wq = (EPI == 2) ? 0.5f / fmaxf(expf(lpq[0]), 1e-10f) : 0.f;
  float local = 0.f;

  #pragma unroll
  for (int mi = 0; mi < 4; ++mi) {
    __syncthreads();
    #pragma unroll
    for (int ni = 0; ni < 4; ++ni)
      #pragma unroll
      for (int r = 0; r < 4; ++r)
        slab[(q * 4 + r) * 68 + ni * 16 + c16] = acc[mi][ni][r];
    __syncthreads();
    #pragma unroll
    for (int pp = 0; pp < 4; ++pp) {
      const int rw = pp * 4 + q;
      const float4 v4 = *(const float4*)&slab[rw * 68 + c4];
      float v[4] = {v4.x, v4.y, v4.z, v4.w};
      const int m = m0 + wm * 64 + mi * 16 + rw;
      const int nc = n0 + wn * 64 + c4;
      if (EPI == 0) {
        const float4 b4 = *(const float4*)&bias[nc];
        v[0] = fmaxf(v[0] + b4.x, 0.f);
        v[1] = fmaxf(v[1] + b4.y, 0.f);
        v[2] = fmaxf(v[2] + b4.z, 0.f);
        v[3] = fmaxf(v[3] + b4.w, 0.f);
        uint2 st;
        st.x = (unsigned)f2bf(v[0]) | ((unsigned)f2bf(v[1]) << 16);
        st.y = (unsigned)f2bf(v[2]) | ((unsigned)f2bf(v[3]) << 16);
        *(uint2*)&outb[(size_t)m * N + nc] = st;
      } else {
        const uint2 h2 = *(const uint2*)&zh[(size_t)m * N + nc];
        const uint2 l2 = *(const uint2*)&zl[(size_t)m * N + nc];
        const float z0 = bf2f((unsigned short)(h2.x & 0xFFFF)) + bf2f((unsigned short)(l2.x & 0xFFFF));
        const float z1 = bf2f((unsigned short)(h2.x >> 16))    + bf2f((unsigned short)(l2.x >> 16));
        const float z2 = bf2f((unsigned short)(h2.y & 0xFFFF)) + bf2f((unsigned short)(l2.y & 0xFFFF));
        const float z3 = bf2f((unsigned short)(h2.y >> 16))    + bf2f((unsigned short)(l2.y >> 16));
        const float d0 = z0 - v[0], d1 = z1 - v[1], d2 = z2 - v[2], d3 = z3 - v[3];
        local += d0 * d0 + d1 * d1 + d2 * d2 + d3 * d3;
        uint2 st;
        st.x = (unsigned)f2bf(v[0]) | ((unsigned)f2bf(v[1]) << 16);
        st.y = (unsigned)f2bf(v[2]) | ((unsigned)f2bf(v[3]) << 16);
        *(uint2*)&outb[(size_t)m * N + nc] = st;
      }
    }
  }
  if (EPI == 2) {
    local = wave_reduce_sum(local) * wq;
    if (l == 0) atomicAdd(kldc, local);
  }
}

// ---------------------------------------------------------------------------
// Row LayerNorm over bf16 input [M][512]. MODE 0: bf16 out. MODE 1: hi/lo
// split out + row norm^2. MODE 2: fp32 out (final x_rec).
// ---------------------------------------------------------------------------
template <int MODE>
__global__ __launch_bounds__(256) void ln_rows(
    const unsigned short* __restrict__ X, const float* __restrict__ g,
    const float* __restrict__ be, unsigned short* __restrict__ Y,
    unsigned short* __restrict__ Yl, float* __restrict__ znorm,
    float* __restrict__ Yf) {
  const int l = threadIdx.x & 63, wv = threadIdx.x >> 6;
  float gv[8], bv[8];
  {
    const float4 a = *(const float4*)&g[l * 8];
    const float4 b = *(const float4*)&g[l * 8 + 4];
    gv[0] = a.x; gv[1] = a.y; gv[2] = a.z; gv[3] = a.w;
    gv[4] = b.x; gv[5] = b.y; gv[6] = b.z; gv[7] = b.w;
    const float4 c = *(const float4*)&be[l * 8];
    const float4 d = *(const float4*)&be[l * 8 + 4];
    bv[0] = c.x; bv[1] = c.y; bv[2] = c.z; bv[3] = c.w;
    bv[4] = d.x; bv[5] = d.y; bv[6] = d.z; bv[7] = d.w;
  }
  const int row0 = blockIdx.x * 32 + wv * 8;
  for (int rr = 0; rr < 8; ++rr) {
    const int row = row0 + rr;
    const uint4 raw = *(const uint4*)&X[(size_t)row * 512 + l * 8];
    float v[8];
    const unsigned rw[4] = {raw.x, raw.y, raw.z, raw.w};
    #pragma unroll
    for (int i = 0; i < 4; ++i) {
      v[2 * i]     = bf2f((unsigned short)(rw[i] & 0xFFFF));
      v[2 * i + 1] = bf2f((unsigned short)(rw[i] >> 16));
    }
    float s = 0.f, ss = 0.f;
    #pragma unroll
    for (int i = 0; i < 8; ++i) { s += v[i]; ss += v[i] * v[i]; }
    #pragma unroll
    for (int m = 1; m < 64; m <<= 1) {
      s += __shfl_xor(s, m, 64);
      ss += __shfl_xor(ss, m, 64);
    }
    const float mean = s * (1.f / 512.f);
    const float var = ss * (1.f / 512.f) - mean * mean;
    const float rstd = rsqrtf(var + 1e-5f);
    float y[8];
    #pragma unroll
    for (int i = 0; i < 8; ++i) y[i] = (v[i] - mean) * rstd * gv[i] + bv[i];
    if (MODE == 0) {
      *(uint4*)&Y[(size_t)row * 512 + l * 8] = pack8(y);
    } else if (MODE == 1) {
      float lo[8], ns = 0.f;
      unsigned short hx[8];
      #pragma unroll
      for (int i = 0; i < 8; ++i) {
        hx[i] = f2bf(y[i]);
        lo[i] = y[i] - bf2f(hx[i]);
        ns += y[i] * y[i];
      }
      uint4 hv;
      hv.x = (unsigned)hx[0] | ((unsigned)hx[1] << 16);
      hv.y = (unsigned)hx[2] | ((unsigned)hx[3] << 16);
      hv.z = (unsigned)hx[4] | ((unsigned)hx[5] << 16);
      hv.w = (unsigned)hx[6] | ((unsigned)hx[7] << 16);
      *(uint4*)&Y[(size_t)row * 512 + l * 8] = hv;
      *(uint4*)&Yl[(size_t)row * 512 + l * 8] = pack8(lo);
      ns = wave_reduce_sum(ns);
      if (l == 0) znorm[row] = ns;
    } else {
      float4 o0, o1;
      o0.x = y[0]; o0.y = y[1]; o0.z = y[2]; o0.w = y[3];
      o1.x = y[4]; o1.y = y[5]; o1.z = y[6]; o1.w = y[7];
      *(float4*)&Yf[(size_t)row * 512 + l * 8] = o0;
      *(float4*)&Yf[(size_t)row * 512 + l * 8 + 4] = o1;
    }
  }
}

// ---------------------------------------------------------------------------
// Prep kernels.
// ---------------------------------------------------------------------------
__global__ __launch_bounds__(256) void convert_f32_bf16(
    const float* __restrict__ X, unsigned short* __restrict__ Y) {
  const size_t i = ((size_t)blockIdx.x * 256 + threadIdx.x) * 8;
  const float4 a = *(const float4*)&X[i];
  const float4 b = *(const float4*)&X[i + 4];
  float v[8] = {a.x, a.y, a.z, a.w, b.x, b.y, b.z, b.w};
  *(uint4*)&Y[i] = pack8(v);
}

// codebook -> hi/lo bf16 + ||c||^2
__global__ __launch_bounds__(256) void prep_cb(
    const float* __restrict__ CB, unsigned short* __restrict__ H,
    unsigned short* __restrict__ L, float* __restrict__ cnorm) {
  const int wv = threadIdx.x >> 6, l = threadIdx.x & 63;
  const int r = blockIdx.x * 4 + wv;
  const float* row = &CB[(size_t)r * 512 + l * 8];
  const float4 a = *(const float4*)row;
  const float4 b = *(const float4*)(row + 4);
  float x[8] = {a.x, a.y, a.z, a.w, b.x, b.y, b.z, b.w};
  float s = 0.f, lo[8];
  unsigned short hi[8];
  #pragma unroll
  for (int i = 0; i < 8; ++i) {
    s += x[i] * x[i];
    hi[i] = f2bf(x[i]);
    lo[i] = x[i] - bf2f(hi[i]);
  }
  uint4 hv;
  hv.x = (unsigned)hi[0] | ((unsigned)hi[1] << 16);
  hv.y = (unsigned)hi[2] | ((unsigned)hi[3] << 16);
  hv.z = (unsigned)hi[4] | ((unsigned)hi[5] << 16);
  hv.w = (unsigned)hi[6] | ((unsigned)hi[7] << 16);
  *(uint4*)&H[(size_t)r * 512 + l * 8] = hv;
  *(uint4*)&L[(size_t)r * 512 + l * 8] = pack8(lo);
  s = wave_reduce_sum(s);
  if (l == 0) cnorm[r] = s;
}

// in [R][C] fp32 -> out [C][R] bf16, LDS-tiled 32x32, coalesced both sides.
__global__ __launch_bounds__(256) void transpose_f32_bf16(
    const float* __restrict__ in, unsigned short* __restrict__ out, int R, int C) {
  __shared__ float tile[32][33];
  const int ntc = C >> 5;
  const int c0 = (blockIdx.x % ntc) * 32, r0 = (blockIdx.x / ntc) * 32;
  const int tx = threadIdx.x & 31, ty = threadIdx.x >> 5;
  #pragma unroll
  for (int i = 0; i < 4; ++i)
    tile[ty + 8 * i][tx] = in[(size_t)(r0 + ty + 8 * i) * C + c0 + tx];
  __syncthreads();
  #pragma unroll
  for (int i = 0; i < 4; ++i)
    out[(size_t)(c0 + ty + 8 * i) * R + r0 + tx] = f2bf(tile[tx][ty + 8 * i]);
}

// ---------------------------------------------------------------------------
// Softmax stats + gumbel-softmax. __expf/__logf fast intrinsics; exp values
// cached in registers. Encodings bf16 into first half of logits rows.
// ---------------------------------------------------------------------------
__global__ __launch_bounds__(256) void softmax_gumbel(
    const float* logits, const float* __restrict__ U, unsigned short* E,
    float* __restrict__ colsum, float* __restrict__ kldd_acc) {
  __shared__ float cs[1024];
  __shared__ float kd[4];
  const int t = threadIdx.x;
  const int wv = t >> 6, l = t & 63;
  #pragma unroll
  for (int i = 0; i < 4; ++i) cs[t + 256 * i] = 0.f;
  __syncthreads();
  float psum[16];
  #pragma unroll
  for (int i = 0; i < 16; ++i) psum[i] = 0.f;
  float kldd = 0.f;
  const int nbase = blockIdx.x * 16 + wv * 4;

  for (int it = 0; it < 4; ++it) {
    const int row = nbase + it;
    const size_t off = (size_t)row * KCODE + 4 * l;
    float v[16];
    #pragma unroll
    for (int jj = 0; jj < 4; ++jj) {
      const float4 t4 = *(const float4*)&logits[off + 256 * jj];
      v[4 * jj + 0] = t4.x; v[4 * jj + 1] = t4.y; v[4 * jj + 2] = t4.z; v[4 * jj + 3] = t4.w;
    }
    float m = v[0];
    #pragma unroll
    for (int i = 1; i < 16; ++i) m = fmaxf(m, v[i]);
    m = wave_reduce_max(m);
    float e[16], se = 0.f;
    #pragma unroll
    for (int i = 0; i < 16; ++i) { e[i] = __expf(v[i] - m); se += e[i]; }
    se = wave_reduce_sum(se);
    const float lz = __logf(se);
    const float inv_se = 1.f / se;
    float pl = 0.f;
    #pragma unroll
    for (int i = 0; i < 16; ++i) {
      const float p = e[i] * inv_se;
      psum[i] += p;
      pl += p * (v[i] - m - lz);
    }
    kldd += pl;
    float y[16];
    #pragma unroll
    for (int jj = 0; jj < 4; ++jj) {
      const float4 t4 = *(const float4*)&U[off + 256 * jj];
      y[4 * jj + 0] = v[4 * jj + 0] - __logf(-__logf(t4.x + 1e-10f) + 1e-10f);
      y[4 * jj + 1] = v[4 * jj + 1] - __logf(-__logf(t4.y + 1e-10f) + 1e-10f);
      y[4 * jj + 2] = v[4 * jj + 2] - __logf(-__logf(t4.z + 1e-10f) + 1e-10f);
      y[4 * jj + 3] = v[4 * jj + 3] - __logf(-__logf(t4.w + 1e-10f) + 1e-10f);
    }
    float m2 = y[0];
    #pragma unroll
    for (int i = 1; i < 16; ++i) m2 = fmaxf(m2, y[i]);
    m2 = wave_reduce_max(m2);
    float ey[16], s2 = 0.f;
    #pragma unroll
    for (int i = 0; i < 16; ++i) { ey[i] = __expf(y[i] - m2); s2 += ey[i]; }
    s2 = wave_reduce_sum(s2);
    const float inv = 1.f / s2;
    #pragma unroll
    for (int jj = 0; jj < 4; ++jj) {
      ushort4 e4;
      e4.x = f2bf(ey[4 * jj + 0] * inv);
      e4.y = f2bf(ey[4 * jj + 1] * inv);
      e4.z = f2bf(ey[4 * jj + 2] * inv);
      e4.w = f2bf(ey[4 * jj + 3] * inv);
      *(ushort4*)&E[(size_t)row * 2048 + 4 * l + 256 * jj] = e4;
    }
  }
  #pragma unroll
  for (int jj = 0; jj < 4; ++jj)
    #pragma unroll
    for (int c = 0; c < 4; ++c)
      atomicAdd(&cs[256 * jj + 4 * l + c], psum[4 * jj + c]);
  kldd = wave_reduce_sum(kldd);
  if (l == 0) kd[wv] = kldd;
  __syncthreads();
  #pragma unroll
  for (int i = 0; i < 4; ++i) {
    const float vv = cs[t + 256 * i];
    if (vv != 0.f) atomicAdd(&colsum[t + 256 * i], vv);
  }
  if (t == 0) atomicAdd(kldd_acc, kd[0] + kd[1] + kd[2] + kd[3]);
}

__global__ __launch_bounds__(256) void finalize(
    const float* __restrict__ colsum, const float* __restrict__ scal,
    float* __restrict__ out) {
  const int t = threadIdx.x;
  float ent = 0.f;
  #pragma unroll
  for (int jj = 0; jj < 4; ++jj) {
    const float a = colsum[t + 256 * jj] * (1.f / 16384.f);
    ent += a * logf(a + 1e-7f);
  }
  ent = wave_reduce_sum(ent);
  __shared__ float red[4];
  if ((t & 63) == 0) red[t >> 6] = ent;
  __syncthreads();
  if (t == 0) {
    const float tot = red[0] + red[1] + red[2] + red[3];
    out[0] = (scal[0] + scal[1]) * (1.f / 8.f);
    out[1] = expf(-tot);
  }
}

extern "C" void kernel_launch(void* const* d_in, const int* in_sizes, int n_in,
                              void* d_out, int out_size, void* d_ws, size_t ws_size,
                              hipStream_t stream) {
  const float* x      = (const float*)d_in[0];
  const float* gu     = (const float*)d_in[1];
  const float* enc_w1 = (const float*)d_in[2];
  const float* enc_b1 = (const float*)d_in[3];
  const float* enc_g1 = (const float*)d_in[4];
  const float* enc_e1 = (const float*)d_in[5];
  const float* enc_w2 = (const float*)d_in[6];
  const float* enc_b2 = (const float*)d_in[7];
  const float* enc_g2 = (const float*)d_in[8];
  const float* enc_e2 = (const float*)d_in[9];
  const float* dec_w1 = (const float*)d_in[10];
  const float* dec_b1 = (const float*)d_in[11];
  const float* dec_g1 = (const float*)d_in[12];
  const float* dec_e1 = (const float*)d_in[13];
  const float* dec_w2 = (const float*)d_in[14];
  const float* dec_b2 = (const float*)d_in[15];
  const float* dec_g2 = (const float*)d_in[16];
  const float* dec_e2 = (const float*)d_in[17];
  const float* cb     = (const float*)d_in[18];
  const float* lpq    = (const float*)d_in[19];
  float* out = (float*)d_out;
  char* wsb = (char*)d_ws;

  float*          logits = (float*)(wsb + 0);                  // 64 MB
  unsigned short* Eb     = (unsigned short*)(wsb + 0);         // overlay, pitch 2048
  unsigned short* t1     = (unsigned short*)(wsb + 67108864);  // 16 MB
  unsigned short* xb     = (unsigned short*)(wsb + 83886080);  // 16 MB (xb then zh)
  unsigned short* zh     = xb;
  unsigned short* hq     = (unsigned short*)(wsb + 100663296); // 16 MB
  unsigned short* zl     = (unsigned short*)(wsb + 117440512); // 16 MB
  unsigned short* wt0    = (unsigned short*)(wsb + 134217728);
  unsigned short* wt1    = wt0 + 262144;
  unsigned short* wt2    = wt1 + 262144;
  unsigned short* wt3    = wt2 + 262144;
  unsigned short* cbh    = (unsigned short*)(wsb + 136314880);
  unsigned short* cbl    = (unsigned short*)(wsb + 137363456);
  unsigned short* cbT    = (unsigned short*)(wsb + 138412032);
  float*          znorm  = (float*)(wsb + 139460608);
  float*          cnorm  = (float*)(wsb + 139526144);
  float*          colsum = (float*)(wsb + 139530240);
  float*          scal   = (float*)(wsb + 139534336);

  hipMemsetAsync(colsum, 0, 4096 + 16, stream);

  convert_f32_bf16<<<4096, 256, 0, stream>>>(x, xb);
  prep_cb<<<256, 256, 0, stream>>>(cb, cbh, cbl, cnorm);
  transpose_f32_bf16<<<256, 256, 0, stream>>>(enc_w1, wt0, 512, 512);
  transpose_f32_bf16<<<256, 256, 0, stream>>>(enc_w2, wt1, 512, 512);
  transpose_f32_bf16<<<256, 256, 0, stream>>>(dec_w1, wt2, 512, 512);
  transpose_f32_bf16<<<256, 256, 0, stream>>>(dec_w2, wt3, 512, 512);
  transpose_f32_bf16<<<512, 256, 0, stream>>>(cb, cbT, 1024, 512);

  gemm_bt<0, 512, 512, 512><<<512, 256, 0, stream>>>(
      xb, wt0, enc_b1, nullptr, nullptr, nullptr, nullptr, t1);
  ln_rows<0><<<512, 256, 0, stream>>>(t1, enc_g1, enc_e1, hq, nullptr, nullptr, nullptr);
  gemm_bt<0, 512, 512, 512><<<512, 256, 0, stream>>>(
      hq, wt1, enc_b2, nullptr, nullptr, nullptr, nullptr, t1);
  ln_rows<1><<<512, 256, 0, stream>>>(t1, enc_g2, enc_e2, zh, zl, znorm, nullptr);
  dist_fused<<<256, 512, 0, stream>>>(
      zh, zl, cbh, cbl, znorm, cnorm, lpq, logits);
  softmax_gumbel<<<1024, 256, 0, stream>>>(logits, gu, Eb, colsum, &scal[0]);
  gemm_bt<2, 1024, 512, 2048><<<512, 256, 0, stream>>>(
      Eb, cbT, nullptr, lpq, zh, zl, &scal[1], hq);
  gemm_bt<0, 512, 512, 512><<<512, 256, 0, stream>>>(
      hq, wt2, dec_b1, nullptr, nullptr, nullptr, nullptr, t1);
  ln_rows<0><<<512, 256, 0, stream>>>(t1, dec_g1, dec_e1, zl, nullptr, nullptr, nullptr);
  gemm_bt<0, 512, 512, 512><<<512, 256, 0, stream>>>(
      zl, wt3, dec_b2, nullptr, nullptr, nullptr, nullptr, t1);
  ln_rows<2><<<512, 256, 0, stream>>>(t1, dec_g2, dec_e2, nullptr, nullptr, nullptr, out);
  finalize<<<1, 256, 0, stream>>>(colsum, scal, out + 8388608);
}

// Round 11
// 440.859 us; speedup vs baseline: 1.0690x; 1.0487x over previous
//
#include <hip/hip_runtime.h>
#include <math.h>

// SQVAE forward on MI355X. N=16384 rows, D=512, K=1024 codes, B=8.
// R16: dist reverted to R12 exact (63.5us proven; R13/R14/R15 all worse).
// The five N=512 GEMMs move 128x128 -> 256x128 tiles (8 waves, grid 256 =
// 1 block/CU like dist): staged bytes x0.75 (they are staged-BW-bound at
// ~6.7 TB/s), same depth-1 glds16 + counted vmcnt + raw-barrier skeleton.
// 5 weight/cb transposes fused into one launch.
#define NROWS 16384
#define DIM   512
#define KCODE 1024

typedef __attribute__((ext_vector_type(8))) __bf16 bf16x8;
typedef __attribute__((ext_vector_type(4))) float f32x4;

__device__ __forceinline__ float wave_reduce_sum(float v) {
  #pragma unroll
  for (int m = 1; m < 64; m <<= 1) v += __shfl_xor(v, m, 64);
  return v;
}
__device__ __forceinline__ float wave_reduce_max(float v) {
  #pragma unroll
  for (int m = 1; m < 64; m <<= 1) v = fmaxf(v, __shfl_xor(v, m, 64));
  return v;
}
__device__ __forceinline__ unsigned short f2bf(float f) {
  union { float f; unsigned u; } v; v.f = f;
  unsigned r = v.u + 0x7FFFu + ((v.u >> 16) & 1u);  // RNE
  return (unsigned short)(r >> 16);
}
__device__ __forceinline__ float bf2f(unsigned short h) {
  union { unsigned u; float f; } v; v.u = ((unsigned)h) << 16;
  return v.f;
}
__device__ __forceinline__ uint4 pack8(const float* x) {
  uint4 r;
  r.x = (unsigned)f2bf(x[0]) | ((unsigned)f2bf(x[1]) << 16);
  r.y = (unsigned)f2bf(x[2]) | ((unsigned)f2bf(x[3]) << 16);
  r.z = (unsigned)f2bf(x[4]) | ((unsigned)f2bf(x[5]) << 16);
  r.w = (unsigned)f2bf(x[6]) | ((unsigned)f2bf(x[7]) << 16);
  return r;
}

// async global->LDS, 16B per lane. LDS dst must be wave-uniform base;
// HW writes base + lane*16.
__device__ __forceinline__ void glds16(const void* g, void* lds) {
  __builtin_amdgcn_global_load_lds(
      (const __attribute__((address_space(1))) unsigned int*)g,
      (__attribute__((address_space(3))) unsigned int*)lds, 16, 0, 0);
}

// ---------------------------------------------------------------------------
// dist_fused (R12 exact): logits = -wq*(zn + cn - 2*(zh@cbh^T + zl@cbh^T +
// zh@cbl^T)). 256x256 tile, 8 waves (2x4), 16 K-steps BK=32, dbuf 2x64KB,
// depth-1 prefetch + counted vmcnt(8) + raw s_barrier.
// ---------------------------------------------------------------------------
__global__ __launch_bounds__(512, 2) void dist_fused(
    const unsigned short* __restrict__ zhp, const unsigned short* __restrict__ zlp,
    const unsigned short* __restrict__ cbh, const unsigned short* __restrict__ cbl,
    const float* __restrict__ znorm, const float* __restrict__ cnorm,
    const float* __restrict__ lpq, float* __restrict__ outf) {
  __shared__ char smem[131072];  // 2 x (zh 16K | zl 16K | cbh 16K | cbl 16K)
  const int t = threadIdx.x;
  const int l = t & 63, w = t >> 6;   // 8 waves
  const int wm = w >> 2, wn = w & 3;  // 2 x 4 wave grid
  const int b = blockIdx.x;
  const int xcd = b & 7, j = b >> 3;
  const int m0 = (xcd * 8 + j / 4) * 256;  // 64 m-tiles, 8 per XCD
  const int n0 = (j % 4) * 256;

  f32x4 acc[8][4];
  #pragma unroll
  for (int i = 0; i < 8; ++i)
    #pragma unroll
    for (int jj = 0; jj < 4; ++jj) acc[i][jj] = (f32x4){0.f, 0.f, 0.f, 0.f};

  // staging: wave w stages chunks {w, w+8} of each operand (chunk = 16rx32k)
  const int row = l & 15;
  const int kcol = (l >> 4) * 8;
  const size_t aLo = (size_t)(m0 + w * 16 + row) * 512 + kcol;
  const size_t aHi = aLo + (size_t)128 * 512;
  const size_t bLo = (size_t)(n0 + w * 16 + row) * 512 + kcol;
  const size_t bHi = bLo + (size_t)128 * 512;

  auto issue = [&](int s) {
    char* hb = smem + (s & 1) * 65536;
    const int kt = s * 32;
    glds16(zhp + aLo + kt, hb + w * 1024);
    glds16(zhp + aHi + kt, hb + (w + 8) * 1024);
    glds16(zlp + aLo + kt, hb + 16384 + w * 1024);
    glds16(zlp + aHi + kt, hb + 16384 + (w + 8) * 1024);
    glds16(cbh + bLo + kt, hb + 32768 + w * 1024);
    glds16(cbh + bHi + kt, hb + 32768 + (w + 8) * 1024);
    glds16(cbl + bLo + kt, hb + 49152 + w * 1024);
    glds16(cbl + bHi + kt, hb + 49152 + (w + 8) * 1024);
  };

  issue(0);  // 8 loads outstanding
  #pragma unroll 1
  for (int s = 0; s < 16; ++s) {
    if (s + 1 < 16) {
      issue(s + 1);  // 16 outstanding; oldest 8 are this step's
      asm volatile("s_waitcnt vmcnt(8)" ::: "memory");
    } else {
      asm volatile("s_waitcnt vmcnt(0)" ::: "memory");
    }
    __builtin_amdgcn_s_barrier();
    const char* hb = smem + (s & 1) * 65536;
    bf16x8 af[8], bh[4], bl_[4];
    #pragma unroll
    for (int i = 0; i < 4; ++i) {
      bh[i]  = *(const bf16x8*)(hb + 32768 + (wn * 4 + i) * 1024 + l * 16);
      bl_[i] = *(const bf16x8*)(hb + 49152 + (wn * 4 + i) * 1024 + l * 16);
    }
    #pragma unroll
    for (int i = 0; i < 8; ++i)
      af[i] = *(const bf16x8*)(hb + (wm * 8 + i) * 1024 + l * 16);  // zh frags
    #pragma unroll
    for (int mi = 0; mi < 8; ++mi)
      #pragma unroll
      for (int ni = 0; ni < 4; ++ni) {
        acc[mi][ni] = __builtin_amdgcn_mfma_f32_16x16x32_bf16(af[mi], bh[ni], acc[mi][ni], 0, 0, 0);
        acc[mi][ni] = __builtin_amdgcn_mfma_f32_16x16x32_bf16(af[mi], bl_[ni], acc[mi][ni], 0, 0, 0);
      }
    #pragma unroll
    for (int i = 0; i < 8; ++i)
      af[i] = *(const bf16x8*)(hb + 16384 + (wm * 8 + i) * 1024 + l * 16);  // zl frags
    #pragma unroll
    for (int mi = 0; mi < 8; ++mi)
      #pragma unroll
      for (int ni = 0; ni < 4; ++ni)
        acc[mi][ni] = __builtin_amdgcn_mfma_f32_16x16x32_bf16(af[mi], bh[ni], acc[mi][ni], 0, 0, 0);
    __builtin_amdgcn_s_barrier();  // reads of cur done before next overwrite
  }

  // ---- Epilogue via per-wave LDS slab (16 rows x 64 cols, stride 68) ----
  float* slab = (float*)(smem + w * 4352);
  const int q = l >> 4, c16 = l & 15;
  const int c4 = (l & 15) * 4;
  const float wq = 0.5f / fmaxf(expf(lpq[0]), 1e-10f);

  #pragma unroll
  for (int mi = 0; mi < 8; ++mi) {
    __syncthreads();
    #pragma unroll
    for (int ni = 0; ni < 4; ++ni)
      #pragma unroll
      for (int r = 0; r < 4; ++r)
        slab[(q * 4 + r) * 68 + ni * 16 + c16] = acc[mi][ni][r];
    __syncthreads();
    #pragma unroll
    for (int pp = 0; pp < 4; ++pp) {
      const int rw = pp * 4 + q;  // 0..15
      const float4 v4 = *(const float4*)&slab[rw * 68 + c4];
      const int m = m0 + wm * 128 + mi * 16 + rw;
      const int nc = n0 + wn * 64 + c4;
      const float zn = znorm[m];
      const float4 cn = *(const float4*)&cnorm[nc];
      float4 o;
      o.x = -wq * (zn + cn.x - 2.f * v4.x);
      o.y = -wq * (zn + cn.y - 2.f * v4.y);
      o.z = -wq * (zn + cn.z - 2.f * v4.z);
      o.w = -wq * (zn + cn.w - 2.f * v4.w);
      *(float4*)&outf[(size_t)m * KCODE + nc] = o;
    }
  }
}

// ---------------------------------------------------------------------------
// gemm_mn: C = A @ B^T, 256x128 tile (M x N), N=512 fixed, 512 thr (8 waves
// 4x2, per-wave 64x64 out), grid 256 (1 block/CU). BK=64, dbuf 2x48KB
// (A 32K | B 16K per half), depth-1 prefetch: 6 glds16/wave/step, vmcnt(6).
// Chunk = 16 rows x 64 k = 2KB as two 1KB K=32 slices. Wave w stages A
// chunks {w, w+8} and B chunk {w}. Staged bytes x0.75 vs the 128^2 tile
// (these GEMMs are staged-BW-bound). EPI 0: bias+relu->bf16 (enc/dec).
// EPI 2: zq->bf16 + kldc (A=Eb pitch LDA, B=cbT).
// ---------------------------------------------------------------------------
template <int EPI, int K, int LDA>
__global__ __launch_bounds__(512, 2) void gemm_mn(
    const unsigned short* A0, const unsigned short* B0,
    const float* __restrict__ bias, const float* __restrict__ lpq,
    const unsigned short* __restrict__ zh, const unsigned short* __restrict__ zl,
    float* __restrict__ kldc, unsigned short* __restrict__ outb) {
  constexpr int N = 512;
  __shared__ char smem[98304];  // 2 halves x (A 32K | B 16K); slab overlays
  const int t = threadIdx.x;
  const int l = t & 63, w = t >> 6;   // 8 waves
  const int wm = w >> 1, wn = w & 1;  // 4 x 2 wave grid
  const int b = blockIdx.x;
  const int xcd = b & 7, j = b >> 3;  // 64 m-tiles x 4 n-tiles
  const int m0 = (xcd * 8 + j / 4) * 256;
  const int n0 = (j % 4) * 128;

  f32x4 acc[4][4];
  #pragma unroll
  for (int i = 0; i < 4; ++i)
    #pragma unroll
    for (int jj = 0; jj < 4; ++jj) acc[i][jj] = (f32x4){0.f, 0.f, 0.f, 0.f};

  const int row = l & 15;
  const int kcol = (l >> 4) * 8;
  const size_t aLo = (size_t)(m0 + w * 16 + row) * LDA + kcol;   // A chunk w
  const size_t aHi = aLo + (size_t)128 * LDA;                    // A chunk w+8
  const size_t bOf = (size_t)(n0 + w * 16 + row) * K + kcol;     // B chunk w

  constexpr int NSTEP = K / 64;

  auto issue = [&](int ss) {
    char* hb = smem + (ss & 1) * 49152;
    const int kt = ss * 64;
    #pragma unroll
    for (int js = 0; js < 2; ++js) {
      const int ko = kt + js * 32;
      const int dj = js * 1024;
      glds16(A0 + aLo + ko, hb + w * 2048 + dj);
      glds16(A0 + aHi + ko, hb + (w + 8) * 2048 + dj);
      glds16(B0 + bOf + ko, hb + 32768 + w * 2048 + dj);
    }
  };

  issue(0);  // 6 loads outstanding
  #pragma unroll 1
  for (int s = 0; s < NSTEP; ++s) {
    if (s + 1 < NSTEP) {
      issue(s + 1);  // 12 outstanding; oldest 6 are this step's
      asm volatile("s_waitcnt vmcnt(6)" ::: "memory");
    } else {
      asm volatile("s_waitcnt vmcnt(0)" ::: "memory");
    }
    __builtin_amdgcn_s_barrier();
    const char* hb = smem + (s & 1) * 49152;
    #pragma unroll
    for (int js = 0; js < 2; ++js) {
      const int dj = js * 1024;
      bf16x8 af[4], bfr[4];
      #pragma unroll
      for (int i = 0; i < 4; ++i) {
        af[i]  = *(const bf16x8*)(hb + (wm * 4 + i) * 2048 + dj + l * 16);
        bfr[i] = *(const bf16x8*)(hb + 32768 + (wn * 4 + i) * 2048 + dj + l * 16);
      }
      #pragma unroll
      for (int mi = 0; mi < 4; ++mi)
        #pragma unroll
        for (int ni = 0; ni < 4; ++ni)
          acc[mi][ni] = __builtin_amdgcn_mfma_f32_16x16x32_bf16(af[mi], bfr[ni], acc[mi][ni], 0, 0, 0);
    }
    __builtin_amdgcn_s_barrier();
  }

  // ---- Epilogue via per-wave LDS slab (16 rows x 64 cols, stride 68) ----
  float* slab = (float*)(smem + w * 4352);
  const int q = l >> 4, c16 = l & 15;
  const int c4 = (l & 15) * 4;
  const float wq = (EPI == 2) ? 0.5f / fmaxf(expf(lpq[0]), 1e-10f) : 0.f;
  float local = 0.f;

  #pragma unroll
  for (int mi = 0; mi < 4; ++mi) {
    __syncthreads();
    #pragma unroll
    for (int ni = 0; ni < 4; ++ni)
      #pragma unroll
      for (int r = 0; r < 4; ++r)
        slab[(q * 4 + r) * 68 + ni * 16 + c16] = acc[mi][ni][r];
    __syncthreads();
    #pragma unroll
    for (int pp = 0; pp < 4; ++pp) {
      const int rw = pp * 4 + q;
      const float4 v4 = *(const float4*)&slab[rw * 68 + c4];
      float v[4] = {v4.x, v4.y, v4.z, v4.w};
      const int m = m0 + wm * 64 + mi * 16 + rw;
      const int nc = n0 + wn * 64 + c4;
      if (EPI == 0) {
        const float4 b4 = *(const float4*)&bias[nc];
        v[0] = fmaxf(v[0] + b4.x, 0.f);
        v[1] = fmaxf(v[1] + b4.y, 0.f);
        v[2] = fmaxf(v[2] + b4.z, 0.f);
        v[3] = fmaxf(v[3] + b4.w, 0.f);
        uint2 st;
        st.x = (unsigned)f2bf(v[0]) | ((unsigned)f2bf(v[1]) << 16);
        st.y = (unsigned)f2bf(v[2]) | ((unsigned)f2bf(v[3]) << 16);
        *(uint2*)&outb[(size_t)m * N + nc] = st;
      } else {
        const uint2 h2 = *(const uint2*)&zh[(size_t)m * N + nc];
        const uint2 l2 = *(const uint2*)&zl[(size_t)m * N + nc];
        const float z0 = bf2f((unsigned short)(h2.x & 0xFFFF)) + bf2f((unsigned short)(l2.x & 0xFFFF));
        const float z1 = bf2f((unsigned short)(h2.x >> 16))    + bf2f((unsigned short)(l2.x >> 16));
        const float z2 = bf2f((unsigned short)(h2.y & 0xFFFF)) + bf2f((unsigned short)(l2.y & 0xFFFF));
        const float z3 = bf2f((unsigned short)(h2.y >> 16))    + bf2f((unsigned short)(l2.y >> 16));
        const float d0 = z0 - v[0], d1 = z1 - v[1], d2 = z2 - v[2], d3 = z3 - v[3];
        local += d0 * d0 + d1 * d1 + d2 * d2 + d3 * d3;
        uint2 st;
        st.x = (unsigned)f2bf(v[0]) | ((unsigned)f2bf(v[1]) << 16);
        st.y = (unsigned)f2bf(v[2]) | ((unsigned)f2bf(v[3]) << 16);
        *(uint2*)&outb[(size_t)m * N + nc] = st;
      }
    }
  }
  if (EPI == 2) {
    local = wave_reduce_sum(local) * wq;
    if (l == 0) atomicAdd(kldc, local);
  }
}

// ---------------------------------------------------------------------------
// Row LayerNorm over bf16 input [M][512]. MODE 0: bf16 out. MODE 1: hi/lo
// split out + row norm^2. MODE 2: fp32 out (final x_rec).
// ---------------------------------------------------------------------------
template <int MODE>
__global__ __launch_bounds__(256) void ln_rows(
    const unsigned short* __restrict__ X, const float* __restrict__ g,
    const float* __restrict__ be, unsigned short* __restrict__ Y,
    unsigned short* __restrict__ Yl, float* __restrict__ znorm,
    float* __restrict__ Yf) {
  const int l = threadIdx.x & 63, wv = threadIdx.x >> 6;
  float gv[8], bv[8];
  {
    const float4 a = *(const float4*)&g[l * 8];
    const float4 b = *(const float4*)&g[l * 8 + 4];
    gv[0] = a.x; gv[1] = a.y; gv[2] = a.z; gv[3] = a.w;
    gv[4] = b.x; gv[5] = b.y; gv[6] = b.z; gv[7] = b.w;
    const float4 c = *(const float4*)&be[l * 8];
    const float4 d = *(const float4*)&be[l * 8 + 4];
    bv[0] = c.x; bv[1] = c.y; bv[2] = c.z; bv[3] = c.w;
    bv[4] = d.x; bv[5] = d.y; bv[6] = d.z; bv[7] = d.w;
  }
  const int row0 = blockIdx.x * 32 + wv * 8;
  for (int rr = 0; rr < 8; ++rr) {
    const int row = row0 + rr;
    const uint4 raw = *(const uint4*)&X[(size_t)row * 512 + l * 8];
    float v[8];
    const unsigned rw[4] = {raw.x, raw.y, raw.z, raw.w};
    #pragma unroll
    for (int i = 0; i < 4; ++i) {
      v[2 * i]     = bf2f((unsigned short)(rw[i] & 0xFFFF));
      v[2 * i + 1] = bf2f((unsigned short)(rw[i] >> 16));
    }
    float s = 0.f, ss = 0.f;
    #pragma unroll
    for (int i = 0; i < 8; ++i) { s += v[i]; ss += v[i] * v[i]; }
    #pragma unroll
    for (int m = 1; m < 64; m <<= 1) {
      s += __shfl_xor(s, m, 64);
      ss += __shfl_xor(ss, m, 64);
    }
    const float mean = s * (1.f / 512.f);
    const float var = ss * (1.f / 512.f) - mean * mean;
    const float rstd = rsqrtf(var + 1e-5f);
    float y[8];
    #pragma unroll
    for (int i = 0; i < 8; ++i) y[i] = (v[i] - mean) * rstd * gv[i] + bv[i];
    if (MODE == 0) {
      *(uint4*)&Y[(size_t)row * 512 + l * 8] = pack8(y);
    } else if (MODE == 1) {
      float lo[8], ns = 0.f;
      unsigned short hx[8];
      #pragma unroll
      for (int i = 0; i < 8; ++i) {
        hx[i] = f2bf(y[i]);
        lo[i] = y[i] - bf2f(hx[i]);
        ns += y[i] * y[i];
      }
      uint4 hv;
      hv.x = (unsigned)hx[0] | ((unsigned)hx[1] << 16);
      hv.y = (unsigned)hx[2] | ((unsigned)hx[3] << 16);
      hv.z = (unsigned)hx[4] | ((unsigned)hx[5] << 16);
      hv.w = (unsigned)hx[6] | ((unsigned)hx[7] << 16);
      *(uint4*)&Y[(size_t)row * 512 + l * 8] = hv;
      *(uint4*)&Yl[(size_t)row * 512 + l * 8] = pack8(lo);
      ns = wave_reduce_sum(ns);
      if (l == 0) znorm[row] = ns;
    } else {
      float4 o0, o1;
      o0.x = y[0]; o0.y = y[1]; o0.z = y[2]; o0.w = y[3];
      o1.x = y[4]; o1.y = y[5]; o1.z = y[6]; o1.w = y[7];
      *(float4*)&Yf[(size_t)row * 512 + l * 8] = o0;
      *(float4*)&Yf[(size_t)row * 512 + l * 8 + 4] = o1;
    }
  }
}

// ---------------------------------------------------------------------------
// Prep kernels.
// ---------------------------------------------------------------------------
__global__ __launch_bounds__(256) void convert_f32_bf16(
    const float* __restrict__ X, unsigned short* __restrict__ Y) {
  const size_t i = ((size_t)blockIdx.x * 256 + threadIdx.x) * 8;
  const float4 a = *(const float4*)&X[i];
  const float4 b = *(const float4*)&X[i + 4];
  float v[8] = {a.x, a.y, a.z, a.w, b.x, b.y, b.z, b.w};
  *(uint4*)&Y[i] = pack8(v);
}

// codebook -> hi/lo bf16 + ||c||^2
__global__ __launch_bounds__(256) void prep_cb(
    const float* __restrict__ CB, unsigned short* __restrict__ H,
    unsigned short* __restrict__ L, float* __restrict__ cnorm) {
  const int wv = threadIdx.x >> 6, l = threadIdx.x & 63;
  const int r = blockIdx.x * 4 + wv;
  const float* row = &CB[(size_t)r * 512 + l * 8];
  const float4 a = *(const float4*)row;
  const float4 b = *(const float4*)(row + 4);
  float x[8] = {a.x, a.y, a.z, a.w, b.x, b.y, b.z, b.w};
  float s = 0.f, lo[8];
  unsigned short hi[8];
  #pragma unroll
  for (int i = 0; i < 8; ++i) {
    s += x[i] * x[i];
    hi[i] = f2bf(x[i]);
    lo[i] = x[i] - bf2f(hi[i]);
  }
  uint4 hv;
  hv.x = (unsigned)hi[0] | ((unsigned)hi[1] << 16);
  hv.y = (unsigned)hi[2] | ((unsigned)hi[3] << 16);
  hv.z = (unsigned)hi[4] | ((unsigned)hi[5] << 16);
  hv.w = (unsigned)hi[6] | ((unsigned)hi[7] << 16);
  *(uint4*)&H[(size_t)r * 512 + l * 8] = hv;
  *(uint4*)&L[(size_t)r * 512 + l * 8] = pack8(lo);
  s = wave_reduce_sum(s);
  if (l == 0) cnorm[r] = s;
}

// Fused transpose of 5 matrices: 4x (512x512 weights) + 1x (1024x512 cb),
// fp32 -> bf16, LDS-tiled 32x32, coalesced both sides. One launch, 1536
// blocks (4x256 + 512), saves 4 launch gaps and fills the chip.
__global__ __launch_bounds__(256) void transpose5(
    const float* __restrict__ i0, const float* __restrict__ i1,
    const float* __restrict__ i2, const float* __restrict__ i3,
    const float* __restrict__ i4,
    unsigned short* __restrict__ o0, unsigned short* __restrict__ o1,
    unsigned short* __restrict__ o2, unsigned short* __restrict__ o3,
    unsigned short* __restrict__ o4) {
  __shared__ float tile[32][33];
  int b = blockIdx.x;
  const float* in;
  unsigned short* out;
  int R, C;
  if (b < 256)       { in = i0; out = o0; R = 512;  C = 512; }
  else if (b < 512)  { b -= 256;  in = i1; out = o1; R = 512;  C = 512; }
  else if (b < 768)  { b -= 512;  in = i2; out = o2; R = 512;  C = 512; }
  else if (b < 1024) { b -= 768;  in = i3; out = o3; R = 512;  C = 512; }
  else               { b -= 1024; in = i4; out = o4; R = 1024; C = 512; }
  const int ntc = C >> 5;
  const int c0 = (b % ntc) * 32, r0 = (b / ntc) * 32;
  const int tx = threadIdx.x & 31, ty = threadIdx.x >> 5;
  #pragma unroll
  for (int i = 0; i < 4; ++i)
    tile[ty + 8 * i][tx] = in[(size_t)(r0 + ty + 8 * i) * C + c0 + tx];
  __syncthreads();
  #pragma unroll
  for (int i = 0; i < 4; ++i)
    out[(size_t)(c0 + ty + 8 * i) * R + r0 + tx] = f2bf(tile[tx][ty + 8 * i]);
}

// ---------------------------------------------------------------------------
// Softmax stats + gumbel-softmax. __expf/__logf fast intrinsics; exp values
// cached in registers. Encodings bf16 into first half of logits rows.
// ---------------------------------------------------------------------------
__global__ __launch_bounds__(256) void softmax_gumbel(
    const float* logits, const float* __restrict__ U, unsigned short* E,
    float* __restrict__ colsum, float* __restrict__ kldd_acc) {
  __shared__ float cs[1024];
  __shared__ float kd[4];
  const int t = threadIdx.x;
  const int wv = t >> 6, l = t & 63;
  #pragma unroll
  for (int i = 0; i < 4; ++i) cs[t + 256 * i] = 0.f;
  __syncthreads();
  float psum[16];
  #pragma unroll
  for (int i = 0; i < 16; ++i) psum[i] = 0.f;
  float kldd = 0.f;
  const int nbase = blockIdx.x * 16 + wv * 4;

  for (int it = 0; it < 4; ++it) {
    const int row = nbase + it;
    const size_t off = (size_t)row * KCODE + 4 * l;
    float v[16];
    #pragma unroll
    for (int jj = 0; jj < 4; ++jj) {
      const float4 t4 = *(const float4*)&logits[off + 256 * jj];
      v[4 * jj + 0] = t4.x; v[4 * jj + 1] = t4.y; v[4 * jj + 2] = t4.z; v[4 * jj + 3] = t4.w;
    }
    float m = v[0];
    #pragma unroll
    for (int i = 1; i < 16; ++i) m = fmaxf(m, v[i]);
    m = wave_reduce_max(m);
    float e[16], se = 0.f;
    #pragma unroll
    for (int i = 0; i < 16; ++i) { e[i] = __expf(v[i] - m); se += e[i]; }
    se = wave_reduce_sum(se);
    const float lz = __logf(se);
    const float inv_se = 1.f / se;
    float pl = 0.f;
    #pragma unroll
    for (int i = 0; i < 16; ++i) {
      const float p = e[i] * inv_se;
      psum[i] += p;
      pl += p * (v[i] - m - lz);
    }
    kldd += pl;
    float y[16];
    #pragma unroll
    for (int jj = 0; jj < 4; ++jj) {
      const float4 t4 = *(const float4*)&U[off + 256 * jj];
      y[4 * jj + 0] = v[4 * jj + 0] - __logf(-__logf(t4.x + 1e-10f) + 1e-10f);
      y[4 * jj + 1] = v[4 * jj + 1] - __logf(-__logf(t4.y + 1e-10f) + 1e-10f);
      y[4 * jj + 2] = v[4 * jj + 2] - __logf(-__logf(t4.z + 1e-10f) + 1e-10f);
      y[4 * jj + 3] = v[4 * jj + 3] - __logf(-__logf(t4.w + 1e-10f) + 1e-10f);
    }
    float m2 = y[0];
    #pragma unroll
    for (int i = 1; i < 16; ++i) m2 = fmaxf(m2, y[i]);
    m2 = wave_reduce_max(m2);
    float ey[16], s2 = 0.f;
    #pragma unroll
    for (int i = 0; i < 16; ++i) { ey[i] = __expf(y[i] - m2); s2 += ey[i]; }
    s2 = wave_reduce_sum(s2);
    const float inv = 1.f / s2;
    #pragma unroll
    for (int jj = 0; jj < 4; ++jj) {
      ushort4 e4;
      e4.x = f2bf(ey[4 * jj + 0] * inv);
      e4.y = f2bf(ey[4 * jj + 1] * inv);
      e4.z = f2bf(ey[4 * jj + 2] * inv);
      e4.w = f2bf(ey[4 * jj + 3] * inv);
      *(ushort4*)&E[(size_t)row * 2048 + 4 * l + 256 * jj] = e4;
    }
  }
  #pragma unroll
  for (int jj = 0; jj < 4; ++jj)
    #pragma unroll
    for (int c = 0; c < 4; ++c)
      atomicAdd(&cs[256 * jj + 4 * l + c], psum[4 * jj + c]);
  kldd = wave_reduce_sum(kldd);
  if (l == 0) kd[wv] = kldd;
  __syncthreads();
  #pragma unroll
  for (int i = 0; i < 4; ++i) {
    const float vv = cs[t + 256 * i];
    if (vv != 0.f) atomicAdd(&colsum[t + 256 * i], vv);
  }
  if (t == 0) atomicAdd(kldd_acc, kd[0] + kd[1] + kd[2] + kd[3]);
}

__global__ __launch_bounds__(256) void finalize(
    const float* __restrict__ colsum, const float* __restrict__ scal,
    float* __restrict__ out) {
  const int t = threadIdx.x;
  float ent = 0.f;
  #pragma unroll
  for (int jj = 0; jj < 4; ++jj) {
    const float a = colsum[t + 256 * jj] * (1.f / 16384.f);
    ent += a * logf(a + 1e-7f);
  }
  ent = wave_reduce_sum(ent);
  __shared__ float red[4];
  if ((t & 63) == 0) red[t >> 6] = ent;
  __syncthreads();
  if (t == 0) {
    const float tot = red[0] + red[1] + red[2] + red[3];
    out[0] = (scal[0] + scal[1]) * (1.f / 8.f);
    out[1] = expf(-tot);
  }
}

extern "C" void kernel_launch(void* const* d_in, const int* in_sizes, int n_in,
                              void* d_out, int out_size, void* d_ws, size_t ws_size,
                              hipStream_t stream) {
  const float* x      = (const float*)d_in[0];
  const float* gu     = (const float*)d_in[1];
  const float* enc_w1 = (const float*)d_in[2];
  const float* enc_b1 = (const float*)d_in[3];
  const float* enc_g1 = (const float*)d_in[4];
  const float* enc_e1 = (const float*)d_in[5];
  const float* enc_w2 = (const float*)d_in[6];
  const float* enc_b2 = (const float*)d_in[7];
  const float* enc_g2 = (const float*)d_in[8];
  const float* enc_e2 = (const float*)d_in[9];
  const float* dec_w1 = (const float*)d_in[10];
  const float* dec_b1 = (const float*)d_in[11];
  const float* dec_g1 = (const float*)d_in[12];
  const float* dec_e1 = (const float*)d_in[13];
  const float* dec_w2 = (const float*)d_in[14];
  const float* dec_b2 = (const float*)d_in[15];
  const float* dec_g2 = (const float*)d_in[16];
  const float* dec_e2 = (const float*)d_in[17];
  const float* cb     = (const float*)d_in[18];
  const float* lpq    = (const float*)d_in[19];
  float* out = (float*)d_out;
  char* wsb = (char*)d_ws;

  float*          logits = (float*)(wsb + 0);                  // 64 MB
  unsigned short* Eb     = (unsigned short*)(wsb + 0);         // overlay, pitch 2048
  unsigned short* t1     = (unsigned short*)(wsb + 67108864);  // 16 MB
  unsigned short* xb     = (unsigned short*)(wsb + 83886080);  // 16 MB (xb then zh)
  unsigned short* zh     = xb;
  unsigned short* hq     = (unsigned short*)(wsb + 100663296); // 16 MB
  unsigned short* zl     = (unsigned short*)(wsb + 117440512); // 16 MB
  unsigned short* wt0    = (unsigned short*)(wsb + 134217728);
  unsigned short* wt1    = wt0 + 262144;
  unsigned short* wt2    = wt1 + 262144;
  unsigned short* wt3    = wt2 + 262144;
  unsigned short* cbh    = (unsigned short*)(wsb + 136314880);
  unsigned short* cbl    = (unsigned short*)(wsb + 137363456);
  unsigned short* cbT    = (unsigned short*)(wsb + 138412032);
  float*          znorm  = (float*)(wsb + 139460608);
  float*          cnorm  = (float*)(wsb + 139526144);
  float*          colsum = (float*)(wsb + 139530240);
  float*          scal   = (float*)(wsb + 139534336);

  hipMemsetAsync(colsum, 0, 4096 + 16, stream);

  convert_f32_bf16<<<4096, 256, 0, stream>>>(x, xb);
  prep_cb<<<256, 256, 0, stream>>>(cb, cbh, cbl, cnorm);
  transpose5<<<1536, 256, 0, stream>>>(
      enc_w1, enc_w2, dec_w1, dec_w2, cb, wt0, wt1, wt2, wt3, cbT);

  gemm_mn<0, 512, 512><<<256, 512, 0, stream>>>(
      xb, wt0, enc_b1, nullptr, nullptr, nullptr, nullptr, t1);
  ln_rows<0><<<512, 256, 0, stream>>>(t1, enc_g1, enc_e1, hq, nullptr, nullptr, nullptr);
  gemm_mn<0, 512, 512><<<256, 512, 0, stream>>>(
      hq, wt1, enc_b2, nullptr, nullptr, nullptr, nullptr, t1);
  ln_rows<1><<<512, 256, 0, stream>>>(t1, enc_g2, enc_e2, zh, zl, znorm, nullptr);
  dist_fused<<<256, 512, 0, stream>>>(
      zh, zl, cbh, cbl, znorm, cnorm, lpq, logits);
  softmax_gumbel<<<1024, 256, 0, stream>>>(logits, gu, Eb, colsum, &scal[0]);
  gemm_mn<2, 1024, 2048><<<256, 512, 0, stream>>>(
      Eb, cbT, nullptr, lpq, zh, zl, &scal[1], hq);
  gemm_mn<0, 512, 512><<<256, 512, 0, stream>>>(
      hq, wt2, dec_b1, nullptr, nullptr, nullptr, nullptr, t1);
  ln_rows<0><<<512, 256, 0, stream>>>(t1, dec_g1, dec_e1, zl, nullptr, nullptr, nullptr);
  gemm_mn<0, 512, 512><<<256, 512, 0, stream>>>(
      zl, wt3, dec_b2, nullptr, nullptr, nullptr, nullptr, t1);
  ln_rows<2><<<512, 256, 0, stream>>>(t1, dec_g2, dec_e2, nullptr, nullptr, nullptr, out);
  finalize<<<1, 256, 0, stream>>>(colsum, scal, out + 8388608);
}